// Round 4
// baseline (4017.290 us; speedup 1.0000x reference)
//
#include <hip/hip_runtime.h>
#include <stdint.h>
#include <math.h>

typedef unsigned long long u64;
typedef unsigned int u32;
typedef unsigned char u8;

#define ATOT 242991    // total anchors per batch
#define PXTOT 80997    // total pixels per batch

__device__ __constant__ int    d_Hs[5]      = {200,100,50,25,13};
__device__ __constant__ int    d_Ws[5]      = {304,152,76,38,19};
__device__ __constant__ int    d_stridec[5] = {4,8,16,32,64};
__device__ __constant__ double d_sized[5]   = {32.0,64.0,128.0,256.0,512.0};
__device__ __constant__ int    d_off[5]     = {0,182400,228000,239400,242250};
__device__ __constant__ int    d_pxoff[6]   = {0,60800,76000,79800,80750,80997};
__device__ __constant__ int    d_Ncand[5]   = {182400,45600,11400,2850,741};
// conv16 tiling: 16x16 tiles, per-batch counts {247,70,20,6,2}
__device__ __constant__ int    d_t2base[5]  = {0,494,634,674,686};
__device__ __constant__ int    d_nt[5]      = {247,70,20,6,2};
__device__ __constant__ int    d_TCW[5]     = {19,10,5,3,2};

__device__ __forceinline__ u32 f2k32(float f) {
  u32 u = __float_as_uint(f);
  return (u & 0x80000000u) ? ~u : (u | 0x80000000u);
}
__device__ __forceinline__ float k2f32(u32 k) {
  u32 u = (k & 0x80000000u) ? (k & 0x7FFFFFFFu) : ~k;
  return __uint_as_float(u);
}
__device__ __forceinline__ u64 d2k(double d) {
  u64 b = (u64)__double_as_longlong(d);
  return (b & 0x8000000000000000ull) ? ~b : (b | 0x8000000000000000ull);
}

// ---------------- weight transpose: w[oc][ic][3][3] -> wt[ic][tap][oc] (f32) ----------
__global__ void wtrans_k(const float* __restrict__ w, float* __restrict__ wt) {
  int gid = blockIdx.x * 256 + threadIdx.x;
  if (gid >= 2304 * 256) return;
  int oc = gid & 255;
  int rest = gid >> 8;
  int ic = rest / 9, tap = rest % 9;
  wt[gid] = w[(oc * 256 + ic) * 9 + tap];
}

// ---------------- PHASE A: fp32 conv3x3+ReLU + cls partials ----------------
// grid: 2760 = 690 tiles x 4 oc-passes. block 256 thr = 4 waves.
// tile 16x16 px; lane -> (row = lane>>2, col0 = (lane&3)*4); wave -> 16 oc (SGPR weights).
// LDS: x halo only (4 ic x 18 x 20 = 1440 floats), unioned with 3072-float reduce buf.
__global__ __launch_bounds__(256) void conv16_k(
    const float* __restrict__ x0, const float* __restrict__ x1,
    const float* __restrict__ x2, const float* __restrict__ x3,
    const float* __restrict__ x4,
    const float* __restrict__ wt, const float* __restrict__ convb,
    const float* __restrict__ clsw, float* __restrict__ zpart)
{
  __shared__ float lds[3072];   // staging uses [0..1439]; reduce uses [0..3071]

  const int bid = blockIdx.x;
  const int pass = bid & 3;
  const int tile2 = bid >> 2;
  int lvl = 0;
#pragma unroll
  for (int l = 1; l < 5; ++l) if (tile2 >= d_t2base[l]) lvl = l;
  const int lid = tile2 - d_t2base[lvl];
  const int nt = d_nt[lvl];
  const int b = lid / nt, tt = lid % nt;
  const int TCW = d_TCW[lvl];
  const int ty = tt / TCW, tx = tt % TCW;
  const int H = d_Hs[lvl], W = d_Ws[lvl], HW = H * W;
  const int y0 = ty * 16, x0c = tx * 16;
  const float* xs[5] = {x0, x1, x2, x3, x4};
  const float* xb = xs[lvl] + (size_t)b * 256 * HW;

  const int t = threadIdx.x;
  const int lane = t & 63;
  const int wid = __builtin_amdgcn_readfirstlane(t >> 6);
  const int row = lane >> 2, col0 = (lane & 3) * 4;
  const int oc0 = pass * 64 + wid * 16;   // uniform per wave

  float acc[4][16];
#pragma unroll
  for (int p = 0; p < 4; ++p)
#pragma unroll
    for (int o = 0; o < 16; ++o) acc[p][o] = 0.f;

  for (int ic0 = 0; ic0 < 256; ic0 += 4) {
    __syncthreads();
    // stage halo: 4 ic x 18 rows x 18 cols (row stride 20)
    for (int q = t; q < 1440; q += 256) {
      int icr = q / 360, rem = q % 360;
      int rr = rem / 20, cc = rem % 20;
      float v = 0.f;
      int gy = y0 + rr - 1, gx = x0c + cc - 1;
      if (cc < 18 && (unsigned)gy < (unsigned)H && (unsigned)gx < (unsigned)W)
        v = xb[(size_t)(ic0 + icr) * HW + gy * W + gx];
      lds[q] = v;
    }
    __syncthreads();
#pragma unroll
    for (int icr = 0; icr < 4; ++icr) {
      const float* wrow = wt + (size_t)(ic0 + icr) * 9 * 256 + oc0;  // uniform
#pragma unroll
      for (int ky = 0; ky < 3; ++ky) {
        const float* xp = &lds[icr * 360 + (row + ky) * 20 + col0];
        float4 xa = *(const float4*)xp;       // halo cols col0..col0+3
        float2 xe = *(const float2*)(xp + 4); // halo cols col0+4..col0+5
        float xw[6] = {xa.x, xa.y, xa.z, xa.w, xe.x, xe.y};
#pragma unroll
        for (int kx = 0; kx < 3; ++kx) {
          const float* wp = wrow + (ky * 3 + kx) * 256;   // uniform, 16B-aligned
#pragma unroll
          for (int q4 = 0; q4 < 4; ++q4) {
            float4 wq = *(const float4*)(wp + q4 * 4);    // uniform -> s_load
            float wv[4] = {wq.x, wq.y, wq.z, wq.w};
#pragma unroll
            for (int j = 0; j < 4; ++j) {
              int o = q4 * 4 + j;
#pragma unroll
              for (int p = 0; p < 4; ++p)
                acc[p][o] = fmaf(xw[p + kx], wv[j], acc[p][o]);
            }
          }
        }
      }
    }
  }

  // bias + relu + cls-head partials (this wave's 16-oc slice)
  float part[12];
#pragma unroll
  for (int k = 0; k < 12; ++k) part[k] = 0.f;
#pragma unroll
  for (int o = 0; o < 16; ++o) {
    float bo = convb[oc0 + o];                 // uniform
    float cw0 = clsw[0 * 256 + oc0 + o];       // uniform
    float cw1 = clsw[1 * 256 + oc0 + o];
    float cw2 = clsw[2 * 256 + oc0 + o];
#pragma unroll
    for (int p = 0; p < 4; ++p) {
      float h = fmaxf(acc[p][o] + bo, 0.f);
      part[p * 3 + 0] = fmaf(h, cw0, part[p * 3 + 0]);
      part[p * 3 + 1] = fmaf(h, cw1, part[p * 3 + 1]);
      part[p * 3 + 2] = fmaf(h, cw2, part[p * 3 + 2]);
    }
  }
  __syncthreads();
#pragma unroll
  for (int k = 0; k < 12; ++k) lds[t * 12 + k] = part[k];
  __syncthreads();
  if (t < 64) {
    float out[12];
#pragma unroll
    for (int k = 0; k < 12; ++k)
      out[k] = lds[t * 12 + k] + lds[(t + 64) * 12 + k] +
               lds[(t + 128) * 12 + k] + lds[(t + 192) * 12 + k];
    int gyo = y0 + row;
    if (gyo < H) {
      const size_t pxbase = (size_t)b * PXTOT + d_pxoff[lvl];
#pragma unroll
      for (int p = 0; p < 4; ++p) {
        int gxo = x0c + col0 + p;
        if (gxo < W) {
          int pix = gyo * W + gxo;
          float* zp = zpart + ((size_t)pass * 2 * PXTOT + pxbase + pix) * 3;
          zp[0] = out[p * 3 + 0];
          zp[1] = out[p * 3 + 1];
          zp[2] = out[p * 3 + 2];
        }
      }
    }
  }
}

// ---------------- screen: sum 4 pass-partials + bias -> sigmoid -> scr32 ----------
__global__ void screen_k(const float* __restrict__ zpart, const float* __restrict__ clsb,
                         float* __restrict__ scr32) {
  int g = blockIdx.x * 256 + threadIdx.x;
  if (g >= 2 * PXTOT) return;
  int b = g / PXTOT, lp = g % PXTOT;
  int lvl = 0;
#pragma unroll
  for (int l = 1; l < 5; ++l) if (lp >= d_pxoff[l]) lvl = l;
  int pix = lp - d_pxoff[lvl];
  size_t obase = (size_t)b * ATOT + d_off[lvl] + (size_t)pix * 3;
#pragma unroll
  for (int hd = 0; hd < 3; ++hd) {
    float z = zpart[((size_t)0 * 2 * PXTOT + g) * 3 + hd]
            + zpart[((size_t)1 * 2 * PXTOT + g) * 3 + hd]
            + zpart[((size_t)2 * 2 * PXTOT + g) * 3 + hd]
            + zpart[((size_t)3 * 2 * PXTOT + g) * 3 + hd]
            + clsb[hd];
    scr32[obase + hd] = 1.f / (1.f + expf(-z));
  }
}

// ---------------- PHASE B: fp32 radix select with safety margin ----------------
__device__ __forceinline__ void locate(int gid, int& b, int& r, int& lvl) {
  b = gid / ATOT; r = gid % ATOT;
  lvl = (r < 182400) ? 0 : (r < 228000) ? 1 : (r < 239400) ? 2 : (r < 242250) ? 3 : 4;
}

__global__ void hist_hi_k(const float* __restrict__ scr, u32* __restrict__ hist) {
  int gid = blockIdx.x * 256 + threadIdx.x;
  if (gid >= 2 * ATOT) return;
  int b, r, lvl; locate(gid, b, r, lvl);
  u32 key = f2k32(scr[gid]);
  atomicAdd(&hist[((b * 5 + lvl) << 16) + (key >> 16)], 1u);
}

__global__ void scan_hi_k(const u32* __restrict__ hist, int* __restrict__ meta) {
  int bl = blockIdx.x, lvl = bl % 5;
  u32 k_sel = (u32)min(1000, d_Ncand[lvl]);
  const u32* h = hist + ((size_t)bl << 16);
  __shared__ u32 part[256];
  int t = threadIdx.x;
  u32 s = 0;
  for (int v = 0; v < 256; ++v) s += h[t * 256 + v];
  part[t] = s;
  __syncthreads();
  if (t == 0) {
    u32 cum = 0; int c = 255;
    for (; c > 0; --c) { if (cum + part[c] >= k_sel) break; cum += part[c]; }
    int pivot = c * 256;
    for (int v = c * 256 + 255; v >= c * 256; --v) {
      if (cum + h[v] >= k_sel) { pivot = v; break; }
      cum += h[v];
    }
    meta[bl * 8 + 0] = pivot;
    meta[bl * 8 + 1] = (int)cum;
  }
}

__global__ void hist_lo_k(const float* __restrict__ scr, const int* __restrict__ meta,
                          u32* __restrict__ hist) {
  int gid = blockIdx.x * 256 + threadIdx.x;
  if (gid >= 2 * ATOT) return;
  int b, r, lvl; locate(gid, b, r, lvl);
  int bl = b * 5 + lvl;
  u32 key = f2k32(scr[gid]);
  if ((int)(key >> 16) == meta[bl * 8 + 0])
    atomicAdd(&hist[(bl << 16) + (key & 0xFFFFu)], 1u);
}

__global__ void scan_lo_k(const u32* __restrict__ hist, int* __restrict__ meta) {
  int bl = blockIdx.x, lvl = bl % 5;
  u32 k_sel = (u32)min(1000, d_Ncand[lvl]);
  const u32* h = hist + ((size_t)bl << 16);
  __shared__ u32 part[256];
  int t = threadIdx.x;
  u32 s = 0;
  for (int v = 0; v < 256; ++v) s += h[t * 256 + v];
  part[t] = s;
  __syncthreads();
  if (t == 0) {
    u32 cum = (u32)meta[bl * 8 + 1];
    int c = 255;
    for (; c > 0; --c) { if (cum + part[c] >= k_sel) break; cum += part[c]; }
    int pivot = c * 256;
    for (int v = c * 256 + 255; v >= c * 256; --v) {
      if (cum + h[v] >= k_sel) { pivot = v; break; }
      cum += h[v];
    }
    u32 P = (((u32)meta[bl * 8 + 0]) << 16) | (u32)pivot;   // exact fp32 kth key
    u32 T = f2k32(k2f32(P) - 1e-3f);                        // safety margin
    if (d_Ncand[lvl] <= 1000) T = 0;                        // keep all
    meta[bl * 8 + 2] = (int)T;
    meta[bl * 8 + 4] = 0;   // compact counter
  }
}

__global__ void compact_k(const float* __restrict__ scr, int* __restrict__ meta,
                          u32* __restrict__ complist, u8* __restrict__ flags) {
  int gid = blockIdx.x * 256 + threadIdx.x;
  if (gid >= 2 * ATOT) return;
  int b, r, lvl; locate(gid, b, r, lvl);
  int bl = b * 5 + lvl;
  u32 key = f2k32(scr[gid]);
  if (key >= (u32)meta[bl * 8 + 2]) {
    int pos = atomicAdd(&meta[bl * 8 + 4], 1);
    if (pos < 8192) {
      u32 li = (u32)(r - d_off[lvl]);
      complist[bl * 8192 + pos] = li;
      flags[b * PXTOT + d_pxoff[lvl] + li / 3] = 1;
    }
  }
}

__global__ void pxcompact_k(u8* __restrict__ flags, u32* __restrict__ worklist,
                            int* __restrict__ wlcount) {
  int gid = blockIdx.x * 256 + threadIdx.x;
  if (gid >= 2 * PXTOT) return;
  if (flags[gid]) {
    flags[gid] = 0;                       // self-clean for next replay
    int pos = atomicAdd(wlcount, 1);
    if (pos < 65536) worklist[pos] = (u32)gid;
  }
}

// ---------------- PHASE C: sparse fp64 rescore of flagged pixels ----------------
#define RSG 2048
__global__ __launch_bounds__(256) void rescore_k(
    const float* __restrict__ x0, const float* __restrict__ x1,
    const float* __restrict__ x2, const float* __restrict__ x3,
    const float* __restrict__ x4,
    const float* __restrict__ wt, const float* __restrict__ convb,
    const float* __restrict__ clsw, const float* __restrict__ clsb,
    const float* __restrict__ regw, const float* __restrict__ regb,
    const u32* __restrict__ worklist, const int* __restrict__ wlcount,
    double* __restrict__ scr64, double* __restrict__ reg64)
{
  __shared__ float xl[4 * 3072];     // 48KB: [slot][ic][12]
  __shared__ double hl[4 * 256];     // 8KB
  const float* xs[5] = {x0, x1, x2, x3, x4};
  const int t = threadIdx.x;
  int count = *wlcount; if (count > 65536) count = 65536;

  for (int base = blockIdx.x * 4; base < count; base += RSG * 4) {
    int sb[4], slvl[4], spix[4];
    bool valid[4];
#pragma unroll
    for (int s = 0; s < 4; ++s) {
      int w = base + s;
      valid[s] = (w < count);
      sb[s] = 0; slvl[s] = 0; spix[s] = 0;
      if (valid[s]) {
        u32 g = worklist[w];
        int b = (int)(g / PXTOT), lp = (int)(g % PXTOT);
        int lvl = 0;
#pragma unroll
        for (int l = 1; l < 5; ++l) if (lp >= d_pxoff[l]) lvl = l;
        sb[s] = b; slvl[s] = lvl; spix[s] = lp - d_pxoff[lvl];
      }
    }
    __syncthreads();
#pragma unroll
    for (int s = 0; s < 4; ++s) {
      if (valid[s]) {
        int lvl = slvl[s], H = d_Hs[lvl], W = d_Ws[lvl];
        int py = spix[s] / W, px = spix[s] % W;
        const float* xb = xs[lvl] + ((size_t)sb[s] * 256 + t) * H * W;
#pragma unroll
        for (int ky = 0; ky < 3; ++ky) {
          int gy = py - 1 + ky;
#pragma unroll
          for (int kx = 0; kx < 3; ++kx) {
            int gx = px - 1 + kx;
            float v = 0.f;
            if ((unsigned)gy < (unsigned)H && (unsigned)gx < (unsigned)W)
              v = xb[gy * W + gx];
            xl[s * 3072 + t * 12 + ky * 3 + kx] = v;
          }
        }
      }
    }
    __syncthreads();
    double h[4] = {0.0, 0.0, 0.0, 0.0};
    for (int ic = 0; ic < 256; ++ic) {
      double wd[9];
#pragma unroll
      for (int tap = 0; tap < 9; ++tap)
        wd[tap] = (double)wt[(ic * 9 + tap) * 256 + t];
#pragma unroll
      for (int s = 0; s < 4; ++s) {
        const float* xp = &xl[s * 3072 + ic * 12];
        float4 a = *(const float4*)xp;
        float4 bq = *(const float4*)(xp + 4);
        float c = xp[8];
        h[s] = fma((double)a.x, wd[0], h[s]);
        h[s] = fma((double)a.y, wd[1], h[s]);
        h[s] = fma((double)a.z, wd[2], h[s]);
        h[s] = fma((double)a.w, wd[3], h[s]);
        h[s] = fma((double)bq.x, wd[4], h[s]);
        h[s] = fma((double)bq.y, wd[5], h[s]);
        h[s] = fma((double)bq.z, wd[6], h[s]);
        h[s] = fma((double)bq.w, wd[7], h[s]);
        h[s] = fma((double)c,    wd[8], h[s]);
      }
    }
    double bias = (double)convb[t];
#pragma unroll
    for (int s = 0; s < 4; ++s) {
      h[s] = fmax(h[s] + bias, 0.0);
      hl[s * 256 + t] = h[s];
    }
    __syncthreads();
    {
      int s = t >> 6, lane = t & 63;
      if (valid[s]) {
        int lvl = slvl[s];
        size_t g3 = (size_t)sb[s] * ATOT + d_off[lvl] + (size_t)spix[s] * 3;
        for (int head = 0; head < 15; ++head) {
          const float* hw = (head < 3) ? (clsw + head * 256) : (regw + (head - 3) * 256);
          double part = 0.0;
#pragma unroll
          for (int q = 0; q < 4; ++q) {
            int oc = lane + q * 64;
            part = fma(hl[s * 256 + oc], (double)hw[oc], part);
          }
          part += __shfl_xor(part, 32);
          part += __shfl_xor(part, 16);
          part += __shfl_xor(part, 8);
          part += __shfl_xor(part, 4);
          part += __shfl_xor(part, 2);
          part += __shfl_xor(part, 1);
          if (lane == 0) {
            double z = part + (double)((head < 3) ? clsb[head] : regb[head - 3]);
            if (head < 3) scr64[g3 + head] = 1.0 / (1.0 + exp(-z));
            else { int hh = head - 3; reg64[(g3 + (hh >> 2)) * 4 + (hh & 3)] = z; }
          }
        }
      }
    }
    __syncthreads();
  }
}

// ---------------- PHASE D: exact fp64 keys, sort, decode, NMS, final ----------------
__global__ void buildkeys_k(const u32* __restrict__ complist, const int* __restrict__ meta,
                            const double* __restrict__ scr64, u64* __restrict__ comp64) {
  int bl = blockIdx.x;
  int b = bl / 5, lvl = bl % 5;
  int M = meta[bl * 8 + 4]; if (M > 8192) M = 8192;
  for (int i = threadIdx.x; i < 8192; i += 256) {
    u64 key = 0;
    if (i < M) {
      u32 li = complist[bl * 8192 + i];
      double sc = scr64[(size_t)b * ATOT + d_off[lvl] + li];
      key = ((d2k(sc) >> 18) << 18) | (u64)(0x3FFFFu - li);
    }
    comp64[bl * 8192 + i] = key;
  }
}

__device__ void bitonic8192_desc(u64* s) {
  int t = threadIdx.x;
  for (int k = 2; k <= 8192; k <<= 1) {
    for (int j = k >> 1; j > 0; j >>= 1) {
      __syncthreads();
#pragma unroll
      for (int q = 0; q < 4; ++q) {
        int i = t + q * 1024;
        int l = (i << 1) - (i & (j - 1));
        int m = l + j;
        bool up = ((l & k) == 0);
        u64 a = s[l], bb = s[m];
        if ((a < bb) == up) { s[l] = bb; s[m] = a; }
      }
    }
  }
  __syncthreads();
}

__global__ __launch_bounds__(1024) void sort_level_k(const u64* __restrict__ comp64,
                                                     const int* __restrict__ meta,
                                                     int* __restrict__ topidx) {
  int bl = blockIdx.x, lvl = bl % 5;
  int k_sel = min(1000, d_Ncand[lvl]);
  __shared__ u64 s[8192];
  int M = meta[bl * 8 + 4]; if (M > 8192) M = 8192;
  for (int i = threadIdx.x; i < 8192; i += 1024)
    s[i] = (i < M) ? comp64[bl * 8192 + i] : 0ull;
  __syncthreads();
  bitonic8192_desc(s);
  for (int r = threadIdx.x; r < 1000; r += 1024) {
    int v = -1;
    if (r < k_sel && r < M) v = (int)(0x3FFFFu - (u32)(s[r] & 0x3FFFFu));
    topidx[bl * 1000 + r] = v;
  }
}

__global__ void decode_k(const int* __restrict__ topidx, const double* __restrict__ scr64,
                         const double* __restrict__ reg64, double* __restrict__ boxes,
                         double* __restrict__ sc0) {
  int gid = blockIdx.x * 256 + threadIdx.x;
  if (gid >= 10000) return;
  int bl = gid / 1000, rank = gid % 1000;
  int b = bl / 5, lvl = bl % 5;
  int idx = topidx[bl * 1000 + rank];
  double X1 = 0.0, Y1 = 0.0, X2 = 0.0, Y2 = 0.0, sc = -1.0;
  if (idx >= 0) {
    size_t g = (size_t)b * ATOT + d_off[lvl] + idx;
    double s = scr64[g];
    double dx = reg64[g * 4 + 0], dy = reg64[g * 4 + 1];
    const double BCLIP = 4.135166556742356;
    double dw = fmin(reg64[g * 4 + 2], BCLIP);
    double dh = fmin(reg64[g * 4 + 3], BCLIP);
    int a = idx % 3, pix = idx / 3;
    int W = d_Ws[lvl];
    int py = pix / W, px = pix % W;
    double r = (a == 0) ? 2.0 : (a == 1) ? 1.0 : 0.5;
    double hr = sqrt(r);
    double size = d_sized[lvl];
    double wsz = size / hr, hsz = size * hr;
    double bx2 = rint(wsz * 0.5), by2 = rint(hsz * 0.5);
    double bx1 = rint(-(wsz * 0.5)), by1 = rint(-(hsz * 0.5));
    double sx = (double)(px * d_stridec[lvl]), sy = (double)(py * d_stridec[lvl]);
    double x1 = sx + bx1, yy1 = sy + by1;
    double x2 = sx + bx2, yy2 = sy + by2;
    double pw = x2 - x1, ph = yy2 - yy1;
    double pcx = x1 + 0.5 * pw, pcy = yy1 + 0.5 * ph;
    double cx = dx * pw + pcx, cy = dy * ph + pcy;
    double w = exp(dw) * pw, h = exp(dh) * ph;
    X1 = fmin(fmax(cx - 0.5 * w, 0.0), 1216.0);
    Y1 = fmin(fmax(cy - 0.5 * h, 0.0), 800.0);
    X2 = fmin(fmax(cx + 0.5 * w, 0.0), 1216.0);
    Y2 = fmin(fmax(cy + 0.5 * h, 0.0), 800.0);
    sc = ((X2 - X1) > 0.001 && (Y2 - Y1) > 0.001) ? s : -1.0;
  }
  double* bp = boxes + (size_t)(bl * 1000 + rank) * 4;
  bp[0] = X1; bp[1] = Y1; bp[2] = X2; bp[3] = Y2;
  sc0[bl * 1000 + rank] = sc;
}

// NMS mask build: 40 blocks (bl x quarter), fp64 IoU
__global__ __launch_bounds__(256) void nms_mask_k(const double* __restrict__ boxes,
                                                  u64* __restrict__ gmask) {
  int blk = blockIdx.x;
  int bl = blk >> 2, qt = blk & 3;
  __shared__ double X1[1000], Y1[1000], X2[1000], Y2[1000], AR[1000];
  int t = threadIdx.x;
  for (int i = t; i < 1000; i += 256) {
    const double* bp = boxes + (size_t)(bl * 1000 + i) * 4;
    double x1 = bp[0], y1 = bp[1], x2 = bp[2], y2 = bp[3];
    X1[i] = x1; Y1[i] = y1; X2[i] = x2; Y2[i] = y2;
    AR[i] = (x2 - x1) * (y2 - y1);
  }
  __syncthreads();
  if (t < 250) {
    int i = qt * 250 + t;
    double ax1 = X1[i], ay1 = Y1[i], ax2 = X2[i], ay2 = Y2[i], aa = AR[i];
    u64* gm = gmask + (size_t)bl * 16000 + (size_t)i * 16;
    for (int wj = 0; wj < 16; ++wj) {
      u64 bits = 0;
      int jb0 = wj * 64;
      for (int jb = 0; jb < 64; ++jb) {
        int j = jb0 + jb;
        if (j <= i || j >= 1000) continue;
        double lx = fmax(ax1, X1[j]), ly = fmax(ay1, Y1[j]);
        double rx = fmin(ax2, X2[j]), ry = fmin(ay2, Y2[j]);
        double ww = fmax(rx - lx, 0.0), hh = fmax(ry - ly, 0.0);
        double inter = ww * hh;
        double uni = (aa + AR[j]) - inter;
        double iou = inter / fmax(uni, 1e-9);
        if (iou > 0.7) bits |= (1ull << jb);
      }
      gm[wj] = bits;
    }
  }
}

// NMS sequential scan: 10 blocks x 64 lanes
__global__ void nms_scan_k(double* __restrict__ sc0, const u64* __restrict__ gmask) {
  int bl = blockIdx.x;
  int lane = threadIdx.x;
  const u64* gm = gmask + (size_t)bl * 16000;
  u64 keepw = 0;
  if (lane < 16) {
    for (int jb = 0; jb < 64; ++jb) {
      int j = lane * 64 + jb;
      if (j < 1000 && sc0[bl * 1000 + j] > -0.5) keepw |= (1ull << jb);
    }
  }
  u64 m0 = 0, m1 = 0, m2 = 0, m3 = 0;
  if (lane < 16) {
    m0 = gm[0 * 16 + lane]; m1 = gm[1 * 16 + lane];
    m2 = gm[2 * 16 + lane]; m3 = gm[3 * 16 + lane];
  }
  for (int i = 0; i < 1000; i += 4) {
    u64 n0 = 0, n1 = 0, n2 = 0, n3 = 0;
    if (lane < 16 && i + 4 < 1000) {
      n0 = gm[(i + 4) * 16 + lane]; n1 = gm[(i + 5) * 16 + lane];
      n2 = gm[(i + 6) * 16 + lane]; n3 = gm[(i + 7) * 16 + lane];
    }
    { u64 kw = __shfl(keepw, (i    ) >> 6); if ((kw >> ((i    ) & 63)) & 1) { if (lane < 16) keepw &= ~m0; } }
    { u64 kw = __shfl(keepw, (i + 1) >> 6); if ((kw >> ((i + 1) & 63)) & 1) { if (lane < 16) keepw &= ~m1; } }
    { u64 kw = __shfl(keepw, (i + 2) >> 6); if ((kw >> ((i + 2) & 63)) & 1) { if (lane < 16) keepw &= ~m2; } }
    { u64 kw = __shfl(keepw, (i + 3) >> 6); if ((kw >> ((i + 3) & 63)) & 1) { if (lane < 16) keepw &= ~m3; } }
    m0 = n0; m1 = n1; m2 = n2; m3 = n3;
  }
  if (lane < 16) {
    for (int jb = 0; jb < 64; ++jb) {
      int j = lane * 64 + jb;
      if (j < 1000) {
        double ss = sc0[bl * 1000 + j];
        sc0[bl * 1000 + j] = ((keepw >> jb) & 1) ? ss : -1.0;
      }
    }
  }
}

__global__ __launch_bounds__(1024) void final_k(const double* __restrict__ sc0,
                                                const double* __restrict__ boxes,
                                                float* __restrict__ out) {
  int b = blockIdx.x;
  __shared__ u64 s[8192];
  for (int i = threadIdx.x; i < 8192; i += 1024) {
    u64 v = 0;
    if (i < 5000) {
      u64 k = d2k(sc0[b * 5000 + i]);
      v = ((k >> 18) << 18) | (u64)(0x3FFFFu - (u32)i);
    }
    s[i] = v;
  }
  __syncthreads();
  bitonic8192_desc(s);
  for (int r = threadIdx.x; r < 1000; r += 1024) {
    u64 v = s[r];
    int idx = (int)(0x3FFFFu - (u32)(v & 0x3FFFFu));
    double score = sc0[b * 5000 + idx];
    const double* bp = boxes + (size_t)(b * 5000 + idx) * 4;
    float* op = out + ((size_t)b * 1000 + r) * 5;
    op[0] = (float)bp[0]; op[1] = (float)bp[1];
    op[2] = (float)bp[2]; op[3] = (float)bp[3];
    op[4] = (float)score;
  }
}

// ---------------- host ----------------
extern "C" void kernel_launch(void* const* d_in, const int* in_sizes, int n_in,
                              void* d_out, int out_size, void* d_ws, size_t ws_size,
                              hipStream_t stream) {
  const float* p[5];
  for (int i = 0; i < 5; ++i) p[i] = (const float*)d_in[i];
  const float* conv_w = (const float*)d_in[5];
  const float* conv_b = (const float*)d_in[6];
  const float* cls_w  = (const float*)d_in[7];
  const float* cls_b  = (const float*)d_in[8];
  const float* reg_w  = (const float*)d_in[9];
  const float* reg_b  = (const float*)d_in[10];
  float* out = (float*)d_out;

  char* ws = (char*)d_ws;
  size_t off = 0;
  auto alloc = [&](size_t bytes) -> void* {
    void* pt = ws + off;
    off = (off + bytes + 255) & ~(size_t)255;
    return pt;
  };
  float*  wt       = (float*) alloc(2304ull * 256 * 4);       // 2.36 MB
  float*  zpart    = (float*) alloc(4ull * 2 * PXTOT * 3 * 4);// 7.78 MB
  float*  scr32    = (float*) alloc(2ull * ATOT * 4);         // 1.94 MB
  double* scr64    = (double*)alloc(2ull * ATOT * 8);         // 3.89 MB
  double* reg64    = (double*)alloc(2ull * ATOT * 4 * 8);     // 15.55 MB
  u32*    hist     = (u32*)   alloc(10ull * 65536 * 4);       // 2.62 MB
  int*    meta     = (int*)   alloc(10ull * 8 * 4);
  u32*    complist = (u32*)   alloc(10ull * 8192 * 4);        // 0.33 MB
  u64*    comp64   = (u64*)   alloc(10ull * 8192 * 8);        // 0.66 MB
  u8*     flags    = (u8*)    alloc(2ull * PXTOT);            // 0.16 MB
  u32*    worklist = (u32*)   alloc(65536ull * 4);            // 0.26 MB
  int*    wlcount  = (int*)   alloc(256);
  int*    topidx   = (int*)   alloc(10ull * 1000 * 4);
  double* boxes    = (double*)alloc(2ull * 5000 * 4 * 8);     // 0.32 MB
  double* sc0      = (double*)alloc(2ull * 5000 * 8);
  u64*    gmask    = (u64*)   alloc(10ull * 1000 * 16 * 8);   // 1.28 MB

  wtrans_k<<<(2304 * 256 + 255) / 256, 256, 0, stream>>>(conv_w, wt);

  conv16_k<<<2760, 256, 0, stream>>>(p[0], p[1], p[2], p[3], p[4],
                                     wt, conv_b, cls_w, zpart);
  screen_k<<<(2 * PXTOT + 255) / 256, 256, 0, stream>>>(zpart, cls_b, scr32);

  int nblk = (2 * ATOT + 255) / 256;
  hipMemsetAsync(hist, 0, 10ull * 65536 * 4, stream);
  hist_hi_k<<<nblk, 256, 0, stream>>>(scr32, hist);
  scan_hi_k<<<10, 256, 0, stream>>>(hist, meta);
  hipMemsetAsync(hist, 0, 10ull * 65536 * 4, stream);
  hist_lo_k<<<nblk, 256, 0, stream>>>(scr32, meta, hist);
  scan_lo_k<<<10, 256, 0, stream>>>(hist, meta);

  hipMemsetAsync(flags, 0, 2ull * PXTOT, stream);
  hipMemsetAsync(wlcount, 0, 4, stream);
  compact_k<<<nblk, 256, 0, stream>>>(scr32, meta, complist, flags);
  pxcompact_k<<<(2 * PXTOT + 255) / 256, 256, 0, stream>>>(flags, worklist, wlcount);

  rescore_k<<<RSG, 256, 0, stream>>>(p[0], p[1], p[2], p[3], p[4],
                                     wt, conv_b, cls_w, cls_b, reg_w, reg_b,
                                     worklist, wlcount, scr64, reg64);

  buildkeys_k<<<10, 256, 0, stream>>>(complist, meta, scr64, comp64);
  sort_level_k<<<10, 1024, 0, stream>>>(comp64, meta, topidx);
  decode_k<<<40, 256, 0, stream>>>(topidx, scr64, reg64, boxes, sc0);
  nms_mask_k<<<40, 256, 0, stream>>>(boxes, gmask);
  nms_scan_k<<<10, 64, 0, stream>>>(sc0, gmask);
  final_k<<<2, 1024, 0, stream>>>(sc0, boxes, out);
}

// Round 5
// 2489.708 us; speedup vs baseline: 1.6136x; 1.6136x over previous
//
#include <hip/hip_runtime.h>
#include <stdint.h>
#include <math.h>

typedef unsigned long long u64;
typedef unsigned int u32;
typedef unsigned char u8;
typedef short s16x8 __attribute__((ext_vector_type(8)));
typedef float f32x4 __attribute__((ext_vector_type(4)));

#define ATOT 242991    // total anchors per batch
#define PXTOT 80997    // total pixels per batch
#define PXPAD 82971    // padded (H+2)x(W+2) pixels per batch

__device__ __constant__ int    d_Hs[5]      = {200,100,50,25,13};
__device__ __constant__ int    d_Ws[5]      = {304,152,76,38,19};
__device__ __constant__ int    d_Wp[5]      = {306,154,78,40,21};
__device__ __constant__ int    d_stridec[5] = {4,8,16,32,64};
__device__ __constant__ double d_sized[5]   = {32.0,64.0,128.0,256.0,512.0};
__device__ __constant__ int    d_off[5]     = {0,182400,228000,239400,242250};
__device__ __constant__ int    d_pxoff[6]   = {0,60800,76000,79800,80750,80997};
__device__ __constant__ int    d_poff[5]    = {0,61812,77520,81576,82656};
__device__ __constant__ int    d_Ncand[5]   = {182400,45600,11400,2850,741};
// xcvt: 32-px chunks per level {1900,475,119,30,8} -> 2532/batch
__device__ __constant__ int    d_xcb[5]     = {0,1900,2375,2494,2524};
// conv: 64-px row tiles: rows x tilesX -> {1000,300,100,25,13} = 1438/batch
__device__ __constant__ int    d_ctb[5]     = {0,1000,1300,1400,1425};
__device__ __constant__ int    d_tX[5]      = {5,3,2,1,1};

__device__ __forceinline__ u32 f2k32(float f) {
  u32 u = __float_as_uint(f);
  return (u & 0x80000000u) ? ~u : (u | 0x80000000u);
}
__device__ __forceinline__ float k2f32(u32 k) {
  u32 u = (k & 0x80000000u) ? (k & 0x7FFFFFFFu) : ~k;
  return __uint_as_float(u);
}
__device__ __forceinline__ u64 d2k(double d) {
  u64 b = (u64)__double_as_longlong(d);
  return (b & 0x8000000000000000ull) ? ~b : (b | 0x8000000000000000ull);
}
__device__ __forceinline__ unsigned short f2bf(float v) {   // RNE
  u32 b = __float_as_uint(v);
  return (unsigned short)((b + 0x7FFFu + ((b >> 16) & 1u)) >> 16);
}
__device__ __forceinline__ float bf2f(unsigned short h) {
  return __uint_as_float(((u32)h) << 16);
}

// ---------------- weight transpose for rescore: w[oc][ic][3][3] -> wt[ic][tap][oc] ----
__global__ void wtrans_k(const float* __restrict__ w, float* __restrict__ wt) {
  int gid = blockIdx.x * 256 + threadIdx.x;
  if (gid >= 2304 * 256) return;
  int oc = gid & 255;
  int rest = gid >> 8;
  int ic = rest / 9, tap = rest % 9;
  wt[gid] = w[(oc * 256 + ic) * 9 + tap];
}

// ---------------- weight -> B-fragment swizzle (bf16 hi/lo) ----------------
// wb[((tap*8+slice)*16+oct)*64 + lane][j] = w[oc=oct*16+(lane&15)][ic=slice*32+(lane>>4)*8+j][tap]
__global__ void wcvt_k(const float* __restrict__ w, short* __restrict__ wbh,
                       short* __restrict__ wbl) {
  int gid = blockIdx.x * 256 + threadIdx.x;   // 73728 = 9*8*16*64
  if (gid >= 73728) return;
  int lane = gid & 63;
  int rest = gid >> 6;                         // (tap*8+slice)*16 + oct
  int oct = rest & 15, rs = rest >> 4;
  int slice = rs & 7, tap = rs >> 3;
  int oc = oct * 16 + (lane & 15);
  int icb = slice * 32 + (lane >> 4) * 8;
  size_t ob = (size_t)gid * 8;
#pragma unroll
  for (int j = 0; j < 8; ++j) {
    float v = w[(oc * 256 + icb + j) * 9 + tap];
    unsigned short h = f2bf(v);
    wbh[ob + j] = (short)h;
    wbl[ob + j] = (short)f2bf(v - bf2f(h));
  }
}

// ---------------- x NCHW fp32 -> NHWC-padded bf16 hi/lo ----------------
__global__ __launch_bounds__(256) void xcvt_k(
    const float* __restrict__ x0, const float* __restrict__ x1,
    const float* __restrict__ x2, const float* __restrict__ x3,
    const float* __restrict__ x4, short* __restrict__ xh, short* __restrict__ xl)
{
  __shared__ float tile[32 * 257];
  const int bid = blockIdx.x;
  const int b = bid / 2532;
  int r = bid % 2532;
  int lvl = 0;
#pragma unroll
  for (int l2 = 1; l2 < 5; ++l2) if (r >= d_xcb[l2]) lvl = l2;
  const int chunk = r - d_xcb[lvl];
  const int H = d_Hs[lvl], W = d_Ws[lvl], HW = H * W, Wp = d_Wp[lvl];
  const int px0 = chunk * 32;
  const float* xs[5] = {x0, x1, x2, x3, x4};
  const float* xb = xs[lvl] + (size_t)b * 256 * HW;
  const int t = threadIdx.x;

  for (int icg = 0; icg < 32; ++icg) {
    int ic = icg * 8 + (t >> 5);
    int px = px0 + (t & 31);
    float v = (px < HW) ? xb[(size_t)ic * HW + px] : 0.f;
    tile[(t & 31) * 257 + ic] = v;
  }
  __syncthreads();
  int px = t >> 3;
  int gpx = px0 + px;
  if (gpx < HW) {
    int yy = gpx / W, xx = gpx % W;
    size_t obase = ((size_t)(b * PXPAD + d_poff[lvl]) +
                    (size_t)(yy + 1) * Wp + (xx + 1)) * 256 + (size_t)(t & 7) * 32;
#pragma unroll
    for (int q = 0; q < 4; ++q) {
      s16x8 hi, lo;
#pragma unroll
      for (int j = 0; j < 8; ++j) {
        float v = tile[px * 257 + (t & 7) * 32 + q * 8 + j];
        unsigned short h = f2bf(v);
        hi[j] = (short)h;
        lo[j] = (short)f2bf(v - bf2f(h));
      }
      *(s16x8*)(xh + obase + q * 8) = hi;
      *(s16x8*)(xl + obase + q * 8) = lo;
    }
  }
}

// ---------------- split-bf16 MFMA conv3x3 + ReLU + in-register cls screen ----------
// block = 4 waves; tile = 64 px (one row) x 256 oc; wave -> 64 oc (4 octiles).
// A: m=lane&15 (px), k=(lane>>4)*8+i ; B: n=lane&15 (oc), same k ; C: col=lane&15,row=(lane>>4)*4+r
__global__ __launch_bounds__(256) void conv_mfma_k(
    const short* __restrict__ xh, const short* __restrict__ xl,
    const short* __restrict__ wbh, const short* __restrict__ wbl,
    const float* __restrict__ convb, const float* __restrict__ clsw,
    const float* __restrict__ clsb, float* __restrict__ scr32)
{
  __shared__ float zl[4][64][3];
  const int bid = blockIdx.x;
  const int b = bid / 1438;
  int r = bid % 1438;
  int lvl = 0;
#pragma unroll
  for (int l2 = 1; l2 < 5; ++l2) if (r >= d_ctb[l2]) lvl = l2;
  const int lid = r - d_ctb[lvl];
  const int tX = d_tX[lvl];
  const int y = lid / tX, x0 = (lid % tX) * 64;
  const int W = d_Ws[lvl], Wp = d_Wp[lvl];
  const size_t pbase = (size_t)(b * PXPAD + d_poff[lvl]);

  const int t = threadIdx.x;
  const int lane = t & 63;
  const int wid = t >> 6;
  const int aoff = (lane & 15) * 256 + (lane >> 4) * 8;

  f32x4 acc[4][4];
#pragma unroll
  for (int m = 0; m < 4; ++m)
#pragma unroll
    for (int o = 0; o < 4; ++o) acc[m][o] = (f32x4){0.f, 0.f, 0.f, 0.f};

#pragma unroll 1
  for (int tap = 0; tap < 9; ++tap) {
    const int ky = tap / 3, kx = tap % 3;
    const size_t re = (pbase + (size_t)(y + ky) * Wp + (x0 + kx)) * 256;
    const short* pah = xh + re;
    const short* pal = xl + re;
    const short* pbh = wbh + (size_t)tap * 8 * 16 * 512;
    const short* pbl = wbl + (size_t)tap * 8 * 16 * 512;
#pragma unroll 1
    for (int slice = 0; slice < 8; ++slice) {
      s16x8 bh[4], bl4[4], ah[4], al4[4];
#pragma unroll
      for (int o = 0; o < 4; ++o) {
        size_t bo = ((size_t)(slice * 16 + wid * 4 + o) * 64 + lane) * 8;
        bh[o]  = *(const s16x8*)(pbh + bo);
        bl4[o] = *(const s16x8*)(pbl + bo);
      }
#pragma unroll
      for (int m = 0; m < 4; ++m) {
        size_t ao = (size_t)aoff + slice * 32 + m * 4096;
        ah[m]  = *(const s16x8*)(pah + ao);
        al4[m] = *(const s16x8*)(pal + ao);
      }
#pragma unroll
      for (int m = 0; m < 4; ++m)
#pragma unroll
        for (int o = 0; o < 4; ++o) {
          acc[m][o] = __builtin_amdgcn_mfma_f32_16x16x32_bf16(ah[m],  bh[o],  acc[m][o], 0, 0, 0);
          acc[m][o] = __builtin_amdgcn_mfma_f32_16x16x32_bf16(ah[m],  bl4[o], acc[m][o], 0, 0, 0);
          acc[m][o] = __builtin_amdgcn_mfma_f32_16x16x32_bf16(al4[m], bh[o],  acc[m][o], 0, 0, 0);
        }
    }
  }

  // epilogue: bias + relu + cls partial over this wave's 64 oc, reduce over 16 lanes
  float bb[4], cw0[4], cw1[4], cw2[4];
#pragma unroll
  for (int o = 0; o < 4; ++o) {
    int oc = wid * 64 + o * 16 + (lane & 15);
    bb[o]  = convb[oc];
    cw0[o] = clsw[0 * 256 + oc];
    cw1[o] = clsw[1 * 256 + oc];
    cw2[o] = clsw[2 * 256 + oc];
  }
#pragma unroll
  for (int m = 0; m < 4; ++m) {
#pragma unroll
    for (int rr = 0; rr < 4; ++rr) {
      float h0 = fmaxf(acc[m][0][rr] + bb[0], 0.f);
      float h1 = fmaxf(acc[m][1][rr] + bb[1], 0.f);
      float h2 = fmaxf(acc[m][2][rr] + bb[2], 0.f);
      float h3 = fmaxf(acc[m][3][rr] + bb[3], 0.f);
      float z0 = fmaf(h0, cw0[0], fmaf(h1, cw0[1], fmaf(h2, cw0[2], h3 * cw0[3])));
      float z1 = fmaf(h0, cw1[0], fmaf(h1, cw1[1], fmaf(h2, cw1[2], h3 * cw1[3])));
      float z2 = fmaf(h0, cw2[0], fmaf(h1, cw2[1], fmaf(h2, cw2[2], h3 * cw2[3])));
      z0 += __shfl_xor(z0, 1); z0 += __shfl_xor(z0, 2); z0 += __shfl_xor(z0, 4); z0 += __shfl_xor(z0, 8);
      z1 += __shfl_xor(z1, 1); z1 += __shfl_xor(z1, 2); z1 += __shfl_xor(z1, 4); z1 += __shfl_xor(z1, 8);
      z2 += __shfl_xor(z2, 1); z2 += __shfl_xor(z2, 2); z2 += __shfl_xor(z2, 4); z2 += __shfl_xor(z2, 8);
      if ((lane & 15) == 0) {
        int slot = m * 16 + (lane >> 4) * 4 + rr;
        zl[wid][slot][0] = z0; zl[wid][slot][1] = z1; zl[wid][slot][2] = z2;
      }
    }
  }
  __syncthreads();
  if (t < 192) {
    int slot = t / 3, head = t % 3;
    int col = x0 + slot;
    if (col < W) {
      float z = zl[0][slot][head] + zl[1][slot][head] + zl[2][slot][head] +
                zl[3][slot][head] + clsb[head];
      int pix = y * W + col;
      scr32[(size_t)b * ATOT + d_off[lvl] + (size_t)pix * 3 + head] =
          1.f / (1.f + expf(-z));
    }
  }
}

// ---------------- PHASE B: fp32 radix select with safety margin ----------------
__device__ __forceinline__ void locate(int gid, int& b, int& r, int& lvl) {
  b = gid / ATOT; r = gid % ATOT;
  lvl = (r < 182400) ? 0 : (r < 228000) ? 1 : (r < 239400) ? 2 : (r < 242250) ? 3 : 4;
}

__global__ void hist_hi_k(const float* __restrict__ scr, u32* __restrict__ hist) {
  int gid = blockIdx.x * 256 + threadIdx.x;
  if (gid >= 2 * ATOT) return;
  int b, r, lvl; locate(gid, b, r, lvl);
  u32 key = f2k32(scr[gid]);
  atomicAdd(&hist[((b * 5 + lvl) << 16) + (key >> 16)], 1u);
}

__global__ void scan_hi_k(const u32* __restrict__ hist, int* __restrict__ meta) {
  int bl = blockIdx.x, lvl = bl % 5;
  u32 k_sel = (u32)min(1000, d_Ncand[lvl]);
  const u32* h = hist + ((size_t)bl << 16);
  __shared__ u32 part[256];
  int t = threadIdx.x;
  u32 s = 0;
  for (int v = 0; v < 256; ++v) s += h[t * 256 + v];
  part[t] = s;
  __syncthreads();
  if (t == 0) {
    u32 cum = 0; int c = 255;
    for (; c > 0; --c) { if (cum + part[c] >= k_sel) break; cum += part[c]; }
    int pivot = c * 256;
    for (int v = c * 256 + 255; v >= c * 256; --v) {
      if (cum + h[v] >= k_sel) { pivot = v; break; }
      cum += h[v];
    }
    meta[bl * 8 + 0] = pivot;
    meta[bl * 8 + 1] = (int)cum;
  }
}

__global__ void hist_lo_k(const float* __restrict__ scr, const int* __restrict__ meta,
                          u32* __restrict__ hist) {
  int gid = blockIdx.x * 256 + threadIdx.x;
  if (gid >= 2 * ATOT) return;
  int b, r, lvl; locate(gid, b, r, lvl);
  int bl = b * 5 + lvl;
  u32 key = f2k32(scr[gid]);
  if ((int)(key >> 16) == meta[bl * 8 + 0])
    atomicAdd(&hist[(bl << 16) + (key & 0xFFFFu)], 1u);
}

__global__ void scan_lo_k(const u32* __restrict__ hist, int* __restrict__ meta) {
  int bl = blockIdx.x, lvl = bl % 5;
  u32 k_sel = (u32)min(1000, d_Ncand[lvl]);
  const u32* h = hist + ((size_t)bl << 16);
  __shared__ u32 part[256];
  int t = threadIdx.x;
  u32 s = 0;
  for (int v = 0; v < 256; ++v) s += h[t * 256 + v];
  part[t] = s;
  __syncthreads();
  if (t == 0) {
    u32 cum = (u32)meta[bl * 8 + 1];
    int c = 255;
    for (; c > 0; --c) { if (cum + part[c] >= k_sel) break; cum += part[c]; }
    int pivot = c * 256;
    for (int v = c * 256 + 255; v >= c * 256; --v) {
      if (cum + h[v] >= k_sel) { pivot = v; break; }
      cum += h[v];
    }
    u32 P = (((u32)meta[bl * 8 + 0]) << 16) | (u32)pivot;   // exact fp32 kth key
    u32 T = f2k32(k2f32(P) - 1e-3f);                        // safety margin
    if (d_Ncand[lvl] <= 1000) T = 0;                        // keep all
    meta[bl * 8 + 2] = (int)T;
    meta[bl * 8 + 4] = 0;   // compact counter
  }
}

__global__ void compact_k(const float* __restrict__ scr, int* __restrict__ meta,
                          u32* __restrict__ complist, u8* __restrict__ flags) {
  int gid = blockIdx.x * 256 + threadIdx.x;
  if (gid >= 2 * ATOT) return;
  int b, r, lvl; locate(gid, b, r, lvl);
  int bl = b * 5 + lvl;
  u32 key = f2k32(scr[gid]);
  if (key >= (u32)meta[bl * 8 + 2]) {
    int pos = atomicAdd(&meta[bl * 8 + 4], 1);
    if (pos < 8192) {
      u32 li = (u32)(r - d_off[lvl]);
      complist[bl * 8192 + pos] = li;
      flags[b * PXTOT + d_pxoff[lvl] + li / 3] = 1;
    }
  }
}

__global__ void pxcompact_k(u8* __restrict__ flags, u32* __restrict__ worklist,
                            int* __restrict__ wlcount) {
  int gid = blockIdx.x * 256 + threadIdx.x;
  if (gid >= 2 * PXTOT) return;
  if (flags[gid]) {
    flags[gid] = 0;
    int pos = atomicAdd(wlcount, 1);
    if (pos < 65536) worklist[pos] = (u32)gid;
  }
}

// ---------------- PHASE C: sparse fp64 rescore of flagged pixels ----------------
#define RSG 2048
__global__ __launch_bounds__(256) void rescore_k(
    const float* __restrict__ x0, const float* __restrict__ x1,
    const float* __restrict__ x2, const float* __restrict__ x3,
    const float* __restrict__ x4,
    const float* __restrict__ wt, const float* __restrict__ convb,
    const float* __restrict__ clsw, const float* __restrict__ clsb,
    const float* __restrict__ regw, const float* __restrict__ regb,
    const u32* __restrict__ worklist, const int* __restrict__ wlcount,
    double* __restrict__ scr64, double* __restrict__ reg64)
{
  __shared__ float xlb[4 * 3072];
  __shared__ double hl[4 * 256];
  const float* xs[5] = {x0, x1, x2, x3, x4};
  const int t = threadIdx.x;
  int count = *wlcount; if (count > 65536) count = 65536;

  for (int base = blockIdx.x * 4; base < count; base += RSG * 4) {
    int sb[4], slvl[4], spix[4];
    bool valid[4];
#pragma unroll
    for (int s = 0; s < 4; ++s) {
      int w = base + s;
      valid[s] = (w < count);
      sb[s] = 0; slvl[s] = 0; spix[s] = 0;
      if (valid[s]) {
        u32 g = worklist[w];
        int b = (int)(g / PXTOT), lp = (int)(g % PXTOT);
        int lvl = 0;
#pragma unroll
        for (int l = 1; l < 5; ++l) if (lp >= d_pxoff[l]) lvl = l;
        sb[s] = b; slvl[s] = lvl; spix[s] = lp - d_pxoff[lvl];
      }
    }
    __syncthreads();
#pragma unroll
    for (int s = 0; s < 4; ++s) {
      if (valid[s]) {
        int lvl = slvl[s], H = d_Hs[lvl], W = d_Ws[lvl];
        int py = spix[s] / W, px = spix[s] % W;
        const float* xb = xs[lvl] + ((size_t)sb[s] * 256 + t) * H * W;
#pragma unroll
        for (int ky = 0; ky < 3; ++ky) {
          int gy = py - 1 + ky;
#pragma unroll
          for (int kx = 0; kx < 3; ++kx) {
            int gx = px - 1 + kx;
            float v = 0.f;
            if ((unsigned)gy < (unsigned)H && (unsigned)gx < (unsigned)W)
              v = xb[gy * W + gx];
            xlb[s * 3072 + t * 12 + ky * 3 + kx] = v;
          }
        }
      }
    }
    __syncthreads();
    double h[4] = {0.0, 0.0, 0.0, 0.0};
    for (int ic = 0; ic < 256; ++ic) {
      double wd[9];
#pragma unroll
      for (int tap = 0; tap < 9; ++tap)
        wd[tap] = (double)wt[(ic * 9 + tap) * 256 + t];
#pragma unroll
      for (int s = 0; s < 4; ++s) {
        const float* xp = &xlb[s * 3072 + ic * 12];
        float4 a = *(const float4*)xp;
        float4 bq = *(const float4*)(xp + 4);
        float c = xp[8];
        h[s] = fma((double)a.x, wd[0], h[s]);
        h[s] = fma((double)a.y, wd[1], h[s]);
        h[s] = fma((double)a.z, wd[2], h[s]);
        h[s] = fma((double)a.w, wd[3], h[s]);
        h[s] = fma((double)bq.x, wd[4], h[s]);
        h[s] = fma((double)bq.y, wd[5], h[s]);
        h[s] = fma((double)bq.z, wd[6], h[s]);
        h[s] = fma((double)bq.w, wd[7], h[s]);
        h[s] = fma((double)c,    wd[8], h[s]);
      }
    }
    double bias = (double)convb[t];
#pragma unroll
    for (int s = 0; s < 4; ++s) {
      h[s] = fmax(h[s] + bias, 0.0);
      hl[s * 256 + t] = h[s];
    }
    __syncthreads();
    {
      int s = t >> 6, lane = t & 63;
      if (valid[s]) {
        int lvl = slvl[s];
        size_t g3 = (size_t)sb[s] * ATOT + d_off[lvl] + (size_t)spix[s] * 3;
        for (int head = 0; head < 15; ++head) {
          const float* hw = (head < 3) ? (clsw + head * 256) : (regw + (head - 3) * 256);
          double part = 0.0;
#pragma unroll
          for (int q = 0; q < 4; ++q) {
            int oc = lane + q * 64;
            part = fma(hl[s * 256 + oc], (double)hw[oc], part);
          }
          part += __shfl_xor(part, 32);
          part += __shfl_xor(part, 16);
          part += __shfl_xor(part, 8);
          part += __shfl_xor(part, 4);
          part += __shfl_xor(part, 2);
          part += __shfl_xor(part, 1);
          if (lane == 0) {
            double z = part + (double)((head < 3) ? clsb[head] : regb[head - 3]);
            if (head < 3) scr64[g3 + head] = 1.0 / (1.0 + exp(-z));
            else { int hh = head - 3; reg64[(g3 + (hh >> 2)) * 4 + (hh & 3)] = z; }
          }
        }
      }
    }
    __syncthreads();
  }
}

// ---------------- PHASE D: exact fp64 keys, sort, decode, NMS, final ----------------
__global__ void buildkeys_k(const u32* __restrict__ complist, const int* __restrict__ meta,
                            const double* __restrict__ scr64, u64* __restrict__ comp64) {
  int bl = blockIdx.x;
  int b = bl / 5, lvl = bl % 5;
  int M = meta[bl * 8 + 4]; if (M > 8192) M = 8192;
  for (int i = threadIdx.x; i < 8192; i += 256) {
    u64 key = 0;
    if (i < M) {
      u32 li = complist[bl * 8192 + i];
      double sc = scr64[(size_t)b * ATOT + d_off[lvl] + li];
      key = ((d2k(sc) >> 18) << 18) | (u64)(0x3FFFFu - li);
    }
    comp64[bl * 8192 + i] = key;
  }
}

__device__ void bitonic8192_desc(u64* s) {
  int t = threadIdx.x;
  for (int k = 2; k <= 8192; k <<= 1) {
    for (int j = k >> 1; j > 0; j >>= 1) {
      __syncthreads();
#pragma unroll
      for (int q = 0; q < 4; ++q) {
        int i = t + q * 1024;
        int l = (i << 1) - (i & (j - 1));
        int m = l + j;
        bool up = ((l & k) == 0);
        u64 a = s[l], bb = s[m];
        if ((a < bb) == up) { s[l] = bb; s[m] = a; }
      }
    }
  }
  __syncthreads();
}

__global__ __launch_bounds__(1024) void sort_level_k(const u64* __restrict__ comp64,
                                                     const int* __restrict__ meta,
                                                     int* __restrict__ topidx) {
  int bl = blockIdx.x, lvl = bl % 5;
  int k_sel = min(1000, d_Ncand[lvl]);
  __shared__ u64 s[8192];
  int M = meta[bl * 8 + 4]; if (M > 8192) M = 8192;
  for (int i = threadIdx.x; i < 8192; i += 1024)
    s[i] = (i < M) ? comp64[bl * 8192 + i] : 0ull;
  __syncthreads();
  bitonic8192_desc(s);
  for (int r = threadIdx.x; r < 1000; r += 1024) {
    int v = -1;
    if (r < k_sel && r < M) v = (int)(0x3FFFFu - (u32)(s[r] & 0x3FFFFu));
    topidx[bl * 1000 + r] = v;
  }
}

__global__ void decode_k(const int* __restrict__ topidx, const double* __restrict__ scr64,
                         const double* __restrict__ reg64, double* __restrict__ boxes,
                         double* __restrict__ sc0) {
  int gid = blockIdx.x * 256 + threadIdx.x;
  if (gid >= 10000) return;
  int bl = gid / 1000, rank = gid % 1000;
  int b = bl / 5, lvl = bl % 5;
  int idx = topidx[bl * 1000 + rank];
  double X1 = 0.0, Y1 = 0.0, X2 = 0.0, Y2 = 0.0, sc = -1.0;
  if (idx >= 0) {
    size_t g = (size_t)b * ATOT + d_off[lvl] + idx;
    double s = scr64[g];
    double dx = reg64[g * 4 + 0], dy = reg64[g * 4 + 1];
    const double BCLIP = 4.135166556742356;
    double dw = fmin(reg64[g * 4 + 2], BCLIP);
    double dh = fmin(reg64[g * 4 + 3], BCLIP);
    int a = idx % 3, pix = idx / 3;
    int W = d_Ws[lvl];
    int py = pix / W, px = pix % W;
    double r = (a == 0) ? 2.0 : (a == 1) ? 1.0 : 0.5;
    double hr = sqrt(r);
    double size = d_sized[lvl];
    double wsz = size / hr, hsz = size * hr;
    double bx2 = rint(wsz * 0.5), by2 = rint(hsz * 0.5);
    double bx1 = rint(-(wsz * 0.5)), by1 = rint(-(hsz * 0.5));
    double sx = (double)(px * d_stridec[lvl]), sy = (double)(py * d_stridec[lvl]);
    double x1 = sx + bx1, yy1 = sy + by1;
    double x2 = sx + bx2, yy2 = sy + by2;
    double pw = x2 - x1, ph = yy2 - yy1;
    double pcx = x1 + 0.5 * pw, pcy = yy1 + 0.5 * ph;
    double cx = dx * pw + pcx, cy = dy * ph + pcy;
    double w = exp(dw) * pw, h = exp(dh) * ph;
    X1 = fmin(fmax(cx - 0.5 * w, 0.0), 1216.0);
    Y1 = fmin(fmax(cy - 0.5 * h, 0.0), 800.0);
    X2 = fmin(fmax(cx + 0.5 * w, 0.0), 1216.0);
    Y2 = fmin(fmax(cy + 0.5 * h, 0.0), 800.0);
    sc = ((X2 - X1) > 0.001 && (Y2 - Y1) > 0.001) ? s : -1.0;
  }
  double* bp = boxes + (size_t)(bl * 1000 + rank) * 4;
  bp[0] = X1; bp[1] = Y1; bp[2] = X2; bp[3] = Y2;
  sc0[bl * 1000 + rank] = sc;
}

__global__ __launch_bounds__(256) void nms_mask_k(const double* __restrict__ boxes,
                                                  u64* __restrict__ gmask) {
  int blk = blockIdx.x;
  int bl = blk >> 2, qt = blk & 3;
  __shared__ double X1[1000], Y1[1000], X2[1000], Y2[1000], AR[1000];
  int t = threadIdx.x;
  for (int i = t; i < 1000; i += 256) {
    const double* bp = boxes + (size_t)(bl * 1000 + i) * 4;
    double x1 = bp[0], y1 = bp[1], x2 = bp[2], y2 = bp[3];
    X1[i] = x1; Y1[i] = y1; X2[i] = x2; Y2[i] = y2;
    AR[i] = (x2 - x1) * (y2 - y1);
  }
  __syncthreads();
  if (t < 250) {
    int i = qt * 250 + t;
    double ax1 = X1[i], ay1 = Y1[i], ax2 = X2[i], ay2 = Y2[i], aa = AR[i];
    u64* gm = gmask + (size_t)bl * 16000 + (size_t)i * 16;
    for (int wj = 0; wj < 16; ++wj) {
      u64 bits = 0;
      int jb0 = wj * 64;
      for (int jb = 0; jb < 64; ++jb) {
        int j = jb0 + jb;
        if (j <= i || j >= 1000) continue;
        double lx = fmax(ax1, X1[j]), ly = fmax(ay1, Y1[j]);
        double rx = fmin(ax2, X2[j]), ry = fmin(ay2, Y2[j]);
        double ww = fmax(rx - lx, 0.0), hh = fmax(ry - ly, 0.0);
        double inter = ww * hh;
        double uni = (aa + AR[j]) - inter;
        double iou = inter / fmax(uni, 1e-9);
        if (iou > 0.7) bits |= (1ull << jb);
      }
      gm[wj] = bits;
    }
  }
}

__global__ void nms_scan_k(double* __restrict__ sc0, const u64* __restrict__ gmask) {
  int bl = blockIdx.x;
  int lane = threadIdx.x;
  const u64* gm = gmask + (size_t)bl * 16000;
  u64 keepw = 0;
  if (lane < 16) {
    for (int jb = 0; jb < 64; ++jb) {
      int j = lane * 64 + jb;
      if (j < 1000 && sc0[bl * 1000 + j] > -0.5) keepw |= (1ull << jb);
    }
  }
  u64 m0 = 0, m1 = 0, m2 = 0, m3 = 0;
  if (lane < 16) {
    m0 = gm[0 * 16 + lane]; m1 = gm[1 * 16 + lane];
    m2 = gm[2 * 16 + lane]; m3 = gm[3 * 16 + lane];
  }
  for (int i = 0; i < 1000; i += 4) {
    u64 n0 = 0, n1 = 0, n2 = 0, n3 = 0;
    if (lane < 16 && i + 4 < 1000) {
      n0 = gm[(i + 4) * 16 + lane]; n1 = gm[(i + 5) * 16 + lane];
      n2 = gm[(i + 6) * 16 + lane]; n3 = gm[(i + 7) * 16 + lane];
    }
    { u64 kw = __shfl(keepw, (i    ) >> 6); if ((kw >> ((i    ) & 63)) & 1) { if (lane < 16) keepw &= ~m0; } }
    { u64 kw = __shfl(keepw, (i + 1) >> 6); if ((kw >> ((i + 1) & 63)) & 1) { if (lane < 16) keepw &= ~m1; } }
    { u64 kw = __shfl(keepw, (i + 2) >> 6); if ((kw >> ((i + 2) & 63)) & 1) { if (lane < 16) keepw &= ~m2; } }
    { u64 kw = __shfl(keepw, (i + 3) >> 6); if ((kw >> ((i + 3) & 63)) & 1) { if (lane < 16) keepw &= ~m3; } }
    m0 = n0; m1 = n1; m2 = n2; m3 = n3;
  }
  if (lane < 16) {
    for (int jb = 0; jb < 64; ++jb) {
      int j = lane * 64 + jb;
      if (j < 1000) {
        double ss = sc0[bl * 1000 + j];
        sc0[bl * 1000 + j] = ((keepw >> jb) & 1) ? ss : -1.0;
      }
    }
  }
}

__global__ __launch_bounds__(1024) void final_k(const double* __restrict__ sc0,
                                                const double* __restrict__ boxes,
                                                float* __restrict__ out) {
  int b = blockIdx.x;
  __shared__ u64 s[8192];
  for (int i = threadIdx.x; i < 8192; i += 1024) {
    u64 v = 0;
    if (i < 5000) {
      u64 k = d2k(sc0[b * 5000 + i]);
      v = ((k >> 18) << 18) | (u64)(0x3FFFFu - (u32)i);
    }
    s[i] = v;
  }
  __syncthreads();
  bitonic8192_desc(s);
  for (int r = threadIdx.x; r < 1000; r += 1024) {
    u64 v = s[r];
    int idx = (int)(0x3FFFFu - (u32)(v & 0x3FFFFu));
    double score = sc0[b * 5000 + idx];
    const double* bp = boxes + (size_t)(b * 5000 + idx) * 4;
    float* op = out + ((size_t)b * 1000 + r) * 5;
    op[0] = (float)bp[0]; op[1] = (float)bp[1];
    op[2] = (float)bp[2]; op[3] = (float)bp[3];
    op[4] = (float)score;
  }
}

// ---------------- host ----------------
extern "C" void kernel_launch(void* const* d_in, const int* in_sizes, int n_in,
                              void* d_out, int out_size, void* d_ws, size_t ws_size,
                              hipStream_t stream) {
  const float* p[5];
  for (int i = 0; i < 5; ++i) p[i] = (const float*)d_in[i];
  const float* conv_w = (const float*)d_in[5];
  const float* conv_b = (const float*)d_in[6];
  const float* cls_w  = (const float*)d_in[7];
  const float* cls_b  = (const float*)d_in[8];
  const float* reg_w  = (const float*)d_in[9];
  const float* reg_b  = (const float*)d_in[10];
  float* out = (float*)d_out;

  char* ws = (char*)d_ws;
  size_t off = 0;
  auto alloc = [&](size_t bytes) -> void* {
    void* pt = ws + off;
    off = (off + bytes + 255) & ~(size_t)255;
    return pt;
  };
  const size_t XTB = (size_t)2 * PXPAD * 256 * 2 + 65536;     // 85.0 MB (padded bf16)
  float*  wt       = (float*) alloc(2304ull * 256 * 4);       // 2.36 MB (rescore)
  short*  wbh      = (short*) alloc(73728ull * 8 * 2);        // 1.18 MB
  short*  wbl      = (short*) alloc(73728ull * 8 * 2);        // 1.18 MB
  short*  xh       = (short*) alloc(XTB);                     // 85 MB
  short*  xl       = (short*) alloc(XTB);                     // 85 MB
  float*  scr32    = (float*) alloc(2ull * ATOT * 4);         // 1.94 MB
  double* scr64    = (double*)alloc(2ull * ATOT * 8);         // 3.89 MB
  double* reg64    = (double*)alloc(2ull * ATOT * 4 * 8);     // 15.55 MB
  u32*    hist     = (u32*)   alloc(10ull * 65536 * 4);       // 2.62 MB
  int*    meta     = (int*)   alloc(10ull * 8 * 4);
  u32*    complist = (u32*)   alloc(10ull * 8192 * 4);
  u64*    comp64   = (u64*)   alloc(10ull * 8192 * 8);
  u8*     flags    = (u8*)    alloc(2ull * PXTOT);
  u32*    worklist = (u32*)   alloc(65536ull * 4);
  int*    wlcount  = (int*)   alloc(256);
  int*    topidx   = (int*)   alloc(10ull * 1000 * 4);
  double* boxes    = (double*)alloc(2ull * 5000 * 4 * 8);
  double* sc0      = (double*)alloc(2ull * 5000 * 8);
  u64*    gmask    = (u64*)   alloc(10ull * 1000 * 16 * 8);

  wtrans_k<<<(2304 * 256 + 255) / 256, 256, 0, stream>>>(conv_w, wt);
  wcvt_k<<<288, 256, 0, stream>>>(conv_w, wbh, wbl);
  hipMemsetAsync(xh, 0, XTB, stream);
  hipMemsetAsync(xl, 0, XTB, stream);
  xcvt_k<<<5064, 256, 0, stream>>>(p[0], p[1], p[2], p[3], p[4], xh, xl);
  conv_mfma_k<<<2876, 256, 0, stream>>>(xh, xl, wbh, wbl, conv_b, cls_w, cls_b, scr32);

  int nblk = (2 * ATOT + 255) / 256;
  hipMemsetAsync(hist, 0, 10ull * 65536 * 4, stream);
  hist_hi_k<<<nblk, 256, 0, stream>>>(scr32, hist);
  scan_hi_k<<<10, 256, 0, stream>>>(hist, meta);
  hipMemsetAsync(hist, 0, 10ull * 65536 * 4, stream);
  hist_lo_k<<<nblk, 256, 0, stream>>>(scr32, meta, hist);
  scan_lo_k<<<10, 256, 0, stream>>>(hist, meta);

  hipMemsetAsync(flags, 0, 2ull * PXTOT, stream);
  hipMemsetAsync(wlcount, 0, 4, stream);
  compact_k<<<nblk, 256, 0, stream>>>(scr32, meta, complist, flags);
  pxcompact_k<<<(2 * PXTOT + 255) / 256, 256, 0, stream>>>(flags, worklist, wlcount);

  rescore_k<<<RSG, 256, 0, stream>>>(p[0], p[1], p[2], p[3], p[4],
                                     wt, conv_b, cls_w, cls_b, reg_w, reg_b,
                                     worklist, wlcount, scr64, reg64);

  buildkeys_k<<<10, 256, 0, stream>>>(complist, meta, scr64, comp64);
  sort_level_k<<<10, 1024, 0, stream>>>(comp64, meta, topidx);
  decode_k<<<40, 256, 0, stream>>>(topidx, scr64, reg64, boxes, sc0);
  nms_mask_k<<<40, 256, 0, stream>>>(boxes, gmask);
  nms_scan_k<<<10, 64, 0, stream>>>(sc0, gmask);
  final_k<<<2, 1024, 0, stream>>>(sc0, boxes, out);
}

// Round 6
// 2320.556 us; speedup vs baseline: 1.7312x; 1.0729x over previous
//
#include <hip/hip_runtime.h>
#include <stdint.h>
#include <math.h>

typedef unsigned long long u64;
typedef unsigned int u32;
typedef unsigned char u8;
typedef short s16x8 __attribute__((ext_vector_type(8)));
typedef float f32x4 __attribute__((ext_vector_type(4)));

#define ATOT 242991    // total anchors per batch
#define PXTOT 80997    // total pixels per batch
#define PXPAD 82971    // padded (H+2)x(W+2) pixels per batch

__device__ __constant__ int    d_Hs[5]      = {200,100,50,25,13};
__device__ __constant__ int    d_Ws[5]      = {304,152,76,38,19};
__device__ __constant__ int    d_Wp[5]      = {306,154,78,40,21};
__device__ __constant__ int    d_stridec[5] = {4,8,16,32,64};
__device__ __constant__ double d_sized[5]   = {32.0,64.0,128.0,256.0,512.0};
__device__ __constant__ int    d_off[5]     = {0,182400,228000,239400,242250};
__device__ __constant__ int    d_pxoff[6]   = {0,60800,76000,79800,80750,80997};
__device__ __constant__ int    d_poff[5]    = {0,61812,77520,81576,82656};
__device__ __constant__ int    d_Ncand[5]   = {182400,45600,11400,2850,741};
// xcvt: 32-px chunks per level {1900,475,119,30,8} -> 2532/batch
__device__ __constant__ int    d_xcb[5]     = {0,1900,2375,2494,2524};
// conv: row-PAIR x 64-px tiles: {100x5,50x3,25x2,13x1,7x1} = 720/batch
__device__ __constant__ int    d_ctb[5]     = {0,500,650,700,713};
__device__ __constant__ int    d_tX[5]      = {5,3,2,1,1};

__device__ __forceinline__ u32 f2k32(float f) {
  u32 u = __float_as_uint(f);
  return (u & 0x80000000u) ? ~u : (u | 0x80000000u);
}
__device__ __forceinline__ float k2f32(u32 k) {
  u32 u = (k & 0x80000000u) ? (k & 0x7FFFFFFFu) : ~k;
  return __uint_as_float(u);
}
__device__ __forceinline__ u64 d2k(double d) {
  u64 b = (u64)__double_as_longlong(d);
  return (b & 0x8000000000000000ull) ? ~b : (b | 0x8000000000000000ull);
}
__device__ __forceinline__ unsigned short f2bf(float v) {   // RNE
  u32 b = __float_as_uint(v);
  return (unsigned short)((b + 0x7FFFu + ((b >> 16) & 1u)) >> 16);
}
__device__ __forceinline__ float bf2f(unsigned short h) {
  return __uint_as_float(((u32)h) << 16);
}

// ---------------- weight transpose for rescore: w[oc][ic][3][3] -> wt[ic][tap][oc] ----
__global__ void wtrans_k(const float* __restrict__ w, float* __restrict__ wt) {
  int gid = blockIdx.x * 256 + threadIdx.x;
  if (gid >= 2304 * 256) return;
  int oc = gid & 255;
  int rest = gid >> 8;
  int ic = rest / 9, tap = rest % 9;
  wt[gid] = w[(oc * 256 + ic) * 9 + tap];
}

// ---------------- weight -> B-fragment swizzle (bf16 hi/lo) ----------------
__global__ void wcvt_k(const float* __restrict__ w, short* __restrict__ wbh,
                       short* __restrict__ wbl) {
  int gid = blockIdx.x * 256 + threadIdx.x;   // 73728 = 9*8*16*64
  if (gid >= 73728) return;
  int lane = gid & 63;
  int rest = gid >> 6;                         // (tap*8+slice)*16 + oct
  int oct = rest & 15, rs = rest >> 4;
  int slice = rs & 7, tap = rs >> 3;
  int oc = oct * 16 + (lane & 15);
  int icb = slice * 32 + (lane >> 4) * 8;
  size_t ob = (size_t)gid * 8;
#pragma unroll
  for (int j = 0; j < 8; ++j) {
    float v = w[(oc * 256 + icb + j) * 9 + tap];
    unsigned short h = f2bf(v);
    wbh[ob + j] = (short)h;
    wbl[ob + j] = (short)f2bf(v - bf2f(h));
  }
}

// ---------------- x NCHW fp32 -> NHWC-padded bf16 (hi only) ----------------
__global__ __launch_bounds__(256) void xcvt_k(
    const float* __restrict__ x0, const float* __restrict__ x1,
    const float* __restrict__ x2, const float* __restrict__ x3,
    const float* __restrict__ x4, short* __restrict__ xh)
{
  __shared__ float tile[32 * 257];
  const int bid = blockIdx.x;
  const int b = bid / 2532;
  int r = bid % 2532;
  int lvl = 0;
#pragma unroll
  for (int l2 = 1; l2 < 5; ++l2) if (r >= d_xcb[l2]) lvl = l2;
  const int chunk = r - d_xcb[lvl];
  const int H = d_Hs[lvl], W = d_Ws[lvl], HW = H * W, Wp = d_Wp[lvl];
  const int px0 = chunk * 32;
  const float* xs[5] = {x0, x1, x2, x3, x4};
  const float* xb = xs[lvl] + (size_t)b * 256 * HW;
  const int t = threadIdx.x;

  for (int icg = 0; icg < 32; ++icg) {
    int ic = icg * 8 + (t >> 5);
    int px = px0 + (t & 31);
    float v = (px < HW) ? xb[(size_t)ic * HW + px] : 0.f;
    tile[(t & 31) * 257 + ic] = v;
  }
  __syncthreads();
  int px = t >> 3;
  int gpx = px0 + px;
  if (gpx < HW) {
    int yy = gpx / W, xx = gpx % W;
    size_t obase = ((size_t)(b * PXPAD + d_poff[lvl]) +
                    (size_t)(yy + 1) * Wp + (xx + 1)) * 256 + (size_t)(t & 7) * 32;
#pragma unroll
    for (int q = 0; q < 4; ++q) {
      s16x8 hi;
#pragma unroll
      for (int j = 0; j < 8; ++j)
        hi[j] = (short)f2bf(tile[px * 257 + (t & 7) * 32 + q * 8 + j]);
      *(s16x8*)(xh + obase + q * 8) = hi;
    }
  }
}

// ---------------- 2-term split-bf16 MFMA conv3x3 + ReLU + in-register cls screen -----
// block = 4 waves; tile = 2 rows x 64 px x 256 oc; wave -> 64 oc, both rows.
// acc: 2 x 4m x 4o x f32x4 = 128 AGPR. z = xh*(wh+wl); dropped xl*w term -> 42-sigma
// under the 5e-3 screen margin.
__global__ __launch_bounds__(256) void conv_mfma_k(
    const short* __restrict__ xh,
    const short* __restrict__ wbh, const short* __restrict__ wbl,
    const float* __restrict__ convb, const float* __restrict__ clsw,
    const float* __restrict__ clsb, float* __restrict__ scr32)
{
  __shared__ float zl[2][4][64][3];
  const int bid = blockIdx.x;
  const int b = bid / 720;
  int r = bid % 720;
  int lvl = 0;
#pragma unroll
  for (int l2 = 1; l2 < 5; ++l2) if (r >= d_ctb[l2]) lvl = l2;
  const int lid = r - d_ctb[lvl];
  const int tX = d_tX[lvl];
  const int pair = lid / tX, xt = lid % tX;
  const int H = d_Hs[lvl], W = d_Ws[lvl], Wp = d_Wp[lvl];
  const int y0 = pair * 2;
  const bool dup = (y0 + 1 >= H);
  const int y1 = dup ? y0 : (y0 + 1);
  const int x0 = xt * 64;
  const size_t pbase = (size_t)(b * PXPAD + d_poff[lvl]);

  const int t = threadIdx.x;
  const int lane = t & 63;
  const int wid = t >> 6;
  const int aoff = (lane & 15) * 256 + (lane >> 4) * 8;

  f32x4 acc0[4][4], acc1[4][4];
#pragma unroll
  for (int m = 0; m < 4; ++m)
#pragma unroll
    for (int o = 0; o < 4; ++o) {
      acc0[m][o] = (f32x4){0.f, 0.f, 0.f, 0.f};
      acc1[m][o] = (f32x4){0.f, 0.f, 0.f, 0.f};
    }

#pragma unroll 1
  for (int tap = 0; tap < 9; ++tap) {
    const int ky = tap / 3, kx = tap % 3;
    const size_t re0 = (pbase + (size_t)(y0 + ky) * Wp + (x0 + kx)) * 256;
    const size_t re1 = (pbase + (size_t)(y1 + ky) * Wp + (x0 + kx)) * 256;
    const short* pa0 = xh + re0;
    const short* pa1 = xh + re1;
    const short* pbh = wbh + (size_t)tap * 8 * 16 * 512;
    const short* pbl = wbl + (size_t)tap * 8 * 16 * 512;
#pragma unroll 1
    for (int slice = 0; slice < 8; ++slice) {
      s16x8 bh[4], bl4[4], a0[4], a1[4];
#pragma unroll
      for (int o = 0; o < 4; ++o) {
        size_t bo = ((size_t)(slice * 16 + wid * 4 + o) * 64 + lane) * 8;
        bh[o]  = *(const s16x8*)(pbh + bo);
        bl4[o] = *(const s16x8*)(pbl + bo);
      }
#pragma unroll
      for (int m = 0; m < 4; ++m) {
        size_t ao = (size_t)aoff + slice * 32 + m * 4096;
        a0[m] = *(const s16x8*)(pa0 + ao);
        a1[m] = *(const s16x8*)(pa1 + ao);
      }
#pragma unroll
      for (int m = 0; m < 4; ++m)
#pragma unroll
        for (int o = 0; o < 4; ++o) {
          acc0[m][o] = __builtin_amdgcn_mfma_f32_16x16x32_bf16(a0[m], bh[o],  acc0[m][o], 0, 0, 0);
          acc0[m][o] = __builtin_amdgcn_mfma_f32_16x16x32_bf16(a0[m], bl4[o], acc0[m][o], 0, 0, 0);
          acc1[m][o] = __builtin_amdgcn_mfma_f32_16x16x32_bf16(a1[m], bh[o],  acc1[m][o], 0, 0, 0);
          acc1[m][o] = __builtin_amdgcn_mfma_f32_16x16x32_bf16(a1[m], bl4[o], acc1[m][o], 0, 0, 0);
        }
    }
  }

  // epilogue: bias + relu + cls partial over this wave's 64 oc, reduce over 16 lanes
  float bb[4], cw0[4], cw1[4], cw2[4];
#pragma unroll
  for (int o = 0; o < 4; ++o) {
    int oc = wid * 64 + o * 16 + (lane & 15);
    bb[o]  = convb[oc];
    cw0[o] = clsw[0 * 256 + oc];
    cw1[o] = clsw[1 * 256 + oc];
    cw2[o] = clsw[2 * 256 + oc];
  }
#define EPILOG(ACC, RR)                                                           \
  {                                                                               \
    _Pragma("unroll")                                                             \
    for (int m = 0; m < 4; ++m) {                                                 \
      _Pragma("unroll")                                                           \
      for (int q = 0; q < 4; ++q) {                                               \
        float h0 = fmaxf(ACC[m][0][q] + bb[0], 0.f);                              \
        float h1 = fmaxf(ACC[m][1][q] + bb[1], 0.f);                              \
        float h2 = fmaxf(ACC[m][2][q] + bb[2], 0.f);                              \
        float h3 = fmaxf(ACC[m][3][q] + bb[3], 0.f);                              \
        float z0 = fmaf(h0, cw0[0], fmaf(h1, cw0[1], fmaf(h2, cw0[2], h3 * cw0[3]))); \
        float z1 = fmaf(h0, cw1[0], fmaf(h1, cw1[1], fmaf(h2, cw1[2], h3 * cw1[3]))); \
        float z2 = fmaf(h0, cw2[0], fmaf(h1, cw2[1], fmaf(h2, cw2[2], h3 * cw2[3]))); \
        z0 += __shfl_xor(z0, 1); z0 += __shfl_xor(z0, 2);                         \
        z0 += __shfl_xor(z0, 4); z0 += __shfl_xor(z0, 8);                         \
        z1 += __shfl_xor(z1, 1); z1 += __shfl_xor(z1, 2);                         \
        z1 += __shfl_xor(z1, 4); z1 += __shfl_xor(z1, 8);                         \
        z2 += __shfl_xor(z2, 1); z2 += __shfl_xor(z2, 2);                         \
        z2 += __shfl_xor(z2, 4); z2 += __shfl_xor(z2, 8);                         \
        if ((lane & 15) == 0) {                                                   \
          int slot = m * 16 + (lane >> 4) * 4 + q;                                \
          zl[RR][wid][slot][0] = z0;                                              \
          zl[RR][wid][slot][1] = z1;                                              \
          zl[RR][wid][slot][2] = z2;                                              \
        }                                                                         \
      }                                                                           \
    }                                                                             \
  }
  EPILOG(acc0, 0)
  EPILOG(acc1, 1)
#undef EPILOG
  __syncthreads();
  if (t < 192) {
    int slot = t / 3, head = t % 3;
    int col = x0 + slot;
    if (col < W) {
#pragma unroll
      for (int rr = 0; rr < 2; ++rr) {
        if (rr == 1 && dup) break;
        float z = zl[rr][0][slot][head] + zl[rr][1][slot][head] +
                  zl[rr][2][slot][head] + zl[rr][3][slot][head] + clsb[head];
        int pix = (y0 + rr) * W + col;
        scr32[(size_t)b * ATOT + d_off[lvl] + (size_t)pix * 3 + head] =
            1.f / (1.f + expf(-z));
      }
    }
  }
}

// ---------------- PHASE B: fp32 radix select with safety margin ----------------
__device__ __forceinline__ void locate(int gid, int& b, int& r, int& lvl) {
  b = gid / ATOT; r = gid % ATOT;
  lvl = (r < 182400) ? 0 : (r < 228000) ? 1 : (r < 239400) ? 2 : (r < 242250) ? 3 : 4;
}

__global__ void hist_hi_k(const float* __restrict__ scr, u32* __restrict__ hist) {
  int gid = blockIdx.x * 256 + threadIdx.x;
  if (gid >= 2 * ATOT) return;
  int b, r, lvl; locate(gid, b, r, lvl);
  u32 key = f2k32(scr[gid]);
  atomicAdd(&hist[((b * 5 + lvl) << 16) + (key >> 16)], 1u);
}

__global__ void scan_hi_k(const u32* __restrict__ hist, int* __restrict__ meta) {
  int bl = blockIdx.x, lvl = bl % 5;
  u32 k_sel = (u32)min(1000, d_Ncand[lvl]);
  const u32* h = hist + ((size_t)bl << 16);
  __shared__ u32 part[256];
  int t = threadIdx.x;
  u32 s = 0;
  for (int v = 0; v < 256; ++v) s += h[t * 256 + v];
  part[t] = s;
  __syncthreads();
  if (t == 0) {
    u32 cum = 0; int c = 255;
    for (; c > 0; --c) { if (cum + part[c] >= k_sel) break; cum += part[c]; }
    int pivot = c * 256;
    for (int v = c * 256 + 255; v >= c * 256; --v) {
      if (cum + h[v] >= k_sel) { pivot = v; break; }
      cum += h[v];
    }
    meta[bl * 8 + 0] = pivot;
    meta[bl * 8 + 1] = (int)cum;
  }
}

__global__ void hist_lo_k(const float* __restrict__ scr, const int* __restrict__ meta,
                          u32* __restrict__ hist) {
  int gid = blockIdx.x * 256 + threadIdx.x;
  if (gid >= 2 * ATOT) return;
  int b, r, lvl; locate(gid, b, r, lvl);
  int bl = b * 5 + lvl;
  u32 key = f2k32(scr[gid]);
  if ((int)(key >> 16) == meta[bl * 8 + 0])
    atomicAdd(&hist[(bl << 16) + (key & 0xFFFFu)], 1u);
}

__global__ void scan_lo_k(const u32* __restrict__ hist, int* __restrict__ meta) {
  int bl = blockIdx.x, lvl = bl % 5;
  u32 k_sel = (u32)min(1000, d_Ncand[lvl]);
  const u32* h = hist + ((size_t)bl << 16);
  __shared__ u32 part[256];
  int t = threadIdx.x;
  u32 s = 0;
  for (int v = 0; v < 256; ++v) s += h[t * 256 + v];
  part[t] = s;
  __syncthreads();
  if (t == 0) {
    u32 cum = (u32)meta[bl * 8 + 1];
    int c = 255;
    for (; c > 0; --c) { if (cum + part[c] >= k_sel) break; cum += part[c]; }
    int pivot = c * 256;
    for (int v = c * 256 + 255; v >= c * 256; --v) {
      if (cum + h[v] >= k_sel) { pivot = v; break; }
      cum += h[v];
    }
    u32 P = (((u32)meta[bl * 8 + 0]) << 16) | (u32)pivot;   // exact fp32 kth key
    u32 T = f2k32(k2f32(P) - 5e-3f);                        // margin covers 2-term err
    if (d_Ncand[lvl] <= 1000) T = 0;                        // keep all
    meta[bl * 8 + 2] = (int)T;
    meta[bl * 8 + 4] = 0;   // compact counter
  }
}

__global__ void compact_k(const float* __restrict__ scr, int* __restrict__ meta,
                          u32* __restrict__ complist, u8* __restrict__ flags) {
  int gid = blockIdx.x * 256 + threadIdx.x;
  if (gid >= 2 * ATOT) return;
  int b, r, lvl; locate(gid, b, r, lvl);
  int bl = b * 5 + lvl;
  u32 key = f2k32(scr[gid]);
  if (key >= (u32)meta[bl * 8 + 2]) {
    int pos = atomicAdd(&meta[bl * 8 + 4], 1);
    if (pos < 8192) {
      u32 li = (u32)(r - d_off[lvl]);
      complist[bl * 8192 + pos] = li;
      flags[b * PXTOT + d_pxoff[lvl] + li / 3] = 1;
    }
  }
}

__global__ void pxcompact_k(u8* __restrict__ flags, u32* __restrict__ worklist,
                            int* __restrict__ wlcount) {
  int gid = blockIdx.x * 256 + threadIdx.x;
  if (gid >= 2 * PXTOT) return;
  if (flags[gid]) {
    flags[gid] = 0;
    int pos = atomicAdd(wlcount, 1);
    if (pos < 65536) worklist[pos] = (u32)gid;
  }
}

// ---------------- PHASE C: sparse fp64 rescore of flagged pixels ----------------
#define RSG 2048
__global__ __launch_bounds__(256) void rescore_k(
    const float* __restrict__ x0, const float* __restrict__ x1,
    const float* __restrict__ x2, const float* __restrict__ x3,
    const float* __restrict__ x4,
    const float* __restrict__ wt, const float* __restrict__ convb,
    const float* __restrict__ clsw, const float* __restrict__ clsb,
    const float* __restrict__ regw, const float* __restrict__ regb,
    const u32* __restrict__ worklist, const int* __restrict__ wlcount,
    double* __restrict__ scr64, double* __restrict__ reg64)
{
  __shared__ float xlb[4 * 3072];
  __shared__ double hl[4 * 256];
  const float* xs[5] = {x0, x1, x2, x3, x4};
  const int t = threadIdx.x;
  int count = *wlcount; if (count > 65536) count = 65536;

  for (int base = blockIdx.x * 4; base < count; base += RSG * 4) {
    int sb[4], slvl[4], spix[4];
    bool valid[4];
#pragma unroll
    for (int s = 0; s < 4; ++s) {
      int w = base + s;
      valid[s] = (w < count);
      sb[s] = 0; slvl[s] = 0; spix[s] = 0;
      if (valid[s]) {
        u32 g = worklist[w];
        int b = (int)(g / PXTOT), lp = (int)(g % PXTOT);
        int lvl = 0;
#pragma unroll
        for (int l = 1; l < 5; ++l) if (lp >= d_pxoff[l]) lvl = l;
        sb[s] = b; slvl[s] = lvl; spix[s] = lp - d_pxoff[lvl];
      }
    }
    __syncthreads();
#pragma unroll
    for (int s = 0; s < 4; ++s) {
      if (valid[s]) {
        int lvl = slvl[s], H = d_Hs[lvl], W = d_Ws[lvl];
        int py = spix[s] / W, px = spix[s] % W;
        const float* xb = xs[lvl] + ((size_t)sb[s] * 256 + t) * H * W;
#pragma unroll
        for (int ky = 0; ky < 3; ++ky) {
          int gy = py - 1 + ky;
#pragma unroll
          for (int kx = 0; kx < 3; ++kx) {
            int gx = px - 1 + kx;
            float v = 0.f;
            if ((unsigned)gy < (unsigned)H && (unsigned)gx < (unsigned)W)
              v = xb[gy * W + gx];
            xlb[s * 3072 + t * 12 + ky * 3 + kx] = v;
          }
        }
      }
    }
    __syncthreads();
    double h[4] = {0.0, 0.0, 0.0, 0.0};
    for (int ic = 0; ic < 256; ++ic) {
      double wd[9];
#pragma unroll
      for (int tap = 0; tap < 9; ++tap)
        wd[tap] = (double)wt[(ic * 9 + tap) * 256 + t];
#pragma unroll
      for (int s = 0; s < 4; ++s) {
        const float* xp = &xlb[s * 3072 + ic * 12];
        float4 a = *(const float4*)xp;
        float4 bq = *(const float4*)(xp + 4);
        float c = xp[8];
        h[s] = fma((double)a.x, wd[0], h[s]);
        h[s] = fma((double)a.y, wd[1], h[s]);
        h[s] = fma((double)a.z, wd[2], h[s]);
        h[s] = fma((double)a.w, wd[3], h[s]);
        h[s] = fma((double)bq.x, wd[4], h[s]);
        h[s] = fma((double)bq.y, wd[5], h[s]);
        h[s] = fma((double)bq.z, wd[6], h[s]);
        h[s] = fma((double)bq.w, wd[7], h[s]);
        h[s] = fma((double)c,    wd[8], h[s]);
      }
    }
    double bias = (double)convb[t];
#pragma unroll
    for (int s = 0; s < 4; ++s) {
      h[s] = fmax(h[s] + bias, 0.0);
      hl[s * 256 + t] = h[s];
    }
    __syncthreads();
    {
      int s = t >> 6, lane = t & 63;
      if (valid[s]) {
        int lvl = slvl[s];
        size_t g3 = (size_t)sb[s] * ATOT + d_off[lvl] + (size_t)spix[s] * 3;
        for (int head = 0; head < 15; ++head) {
          const float* hw = (head < 3) ? (clsw + head * 256) : (regw + (head - 3) * 256);
          double part = 0.0;
#pragma unroll
          for (int q = 0; q < 4; ++q) {
            int oc = lane + q * 64;
            part = fma(hl[s * 256 + oc], (double)hw[oc], part);
          }
          part += __shfl_xor(part, 32);
          part += __shfl_xor(part, 16);
          part += __shfl_xor(part, 8);
          part += __shfl_xor(part, 4);
          part += __shfl_xor(part, 2);
          part += __shfl_xor(part, 1);
          if (lane == 0) {
            double z = part + (double)((head < 3) ? clsb[head] : regb[head - 3]);
            if (head < 3) scr64[g3 + head] = 1.0 / (1.0 + exp(-z));
            else { int hh = head - 3; reg64[(g3 + (hh >> 2)) * 4 + (hh & 3)] = z; }
          }
        }
      }
    }
    __syncthreads();
  }
}

// ---------------- PHASE D: exact fp64 keys, sort, decode, NMS, final ----------------
__global__ void buildkeys_k(const u32* __restrict__ complist, const int* __restrict__ meta,
                            const double* __restrict__ scr64, u64* __restrict__ comp64) {
  int bl = blockIdx.x;
  int b = bl / 5, lvl = bl % 5;
  int M = meta[bl * 8 + 4]; if (M > 8192) M = 8192;
  for (int i = threadIdx.x; i < 8192; i += 256) {
    u64 key = 0;
    if (i < M) {
      u32 li = complist[bl * 8192 + i];
      double sc = scr64[(size_t)b * ATOT + d_off[lvl] + li];
      key = ((d2k(sc) >> 18) << 18) | (u64)(0x3FFFFu - li);
    }
    comp64[bl * 8192 + i] = key;
  }
}

__device__ void bitonic8192_desc(u64* s) {
  int t = threadIdx.x;
  for (int k = 2; k <= 8192; k <<= 1) {
    for (int j = k >> 1; j > 0; j >>= 1) {
      __syncthreads();
#pragma unroll
      for (int q = 0; q < 4; ++q) {
        int i = t + q * 1024;
        int l = (i << 1) - (i & (j - 1));
        int m = l + j;
        bool up = ((l & k) == 0);
        u64 a = s[l], bb = s[m];
        if ((a < bb) == up) { s[l] = bb; s[m] = a; }
      }
    }
  }
  __syncthreads();
}

__global__ __launch_bounds__(1024) void sort_level_k(const u64* __restrict__ comp64,
                                                     const int* __restrict__ meta,
                                                     int* __restrict__ topidx) {
  int bl = blockIdx.x, lvl = bl % 5;
  int k_sel = min(1000, d_Ncand[lvl]);
  __shared__ u64 s[8192];
  int M = meta[bl * 8 + 4]; if (M > 8192) M = 8192;
  for (int i = threadIdx.x; i < 8192; i += 1024)
    s[i] = (i < M) ? comp64[bl * 8192 + i] : 0ull;
  __syncthreads();
  bitonic8192_desc(s);
  for (int r = threadIdx.x; r < 1000; r += 1024) {
    int v = -1;
    if (r < k_sel && r < M) v = (int)(0x3FFFFu - (u32)(s[r] & 0x3FFFFu));
    topidx[bl * 1000 + r] = v;
  }
}

__global__ void decode_k(const int* __restrict__ topidx, const double* __restrict__ scr64,
                         const double* __restrict__ reg64, double* __restrict__ boxes,
                         double* __restrict__ sc0) {
  int gid = blockIdx.x * 256 + threadIdx.x;
  if (gid >= 10000) return;
  int bl = gid / 1000, rank = gid % 1000;
  int b = bl / 5, lvl = bl % 5;
  int idx = topidx[bl * 1000 + rank];
  double X1 = 0.0, Y1 = 0.0, X2 = 0.0, Y2 = 0.0, sc = -1.0;
  if (idx >= 0) {
    size_t g = (size_t)b * ATOT + d_off[lvl] + idx;
    double s = scr64[g];
    double dx = reg64[g * 4 + 0], dy = reg64[g * 4 + 1];
    const double BCLIP = 4.135166556742356;
    double dw = fmin(reg64[g * 4 + 2], BCLIP);
    double dh = fmin(reg64[g * 4 + 3], BCLIP);
    int a = idx % 3, pix = idx / 3;
    int W = d_Ws[lvl];
    int py = pix / W, px = pix % W;
    double r = (a == 0) ? 2.0 : (a == 1) ? 1.0 : 0.5;
    double hr = sqrt(r);
    double size = d_sized[lvl];
    double wsz = size / hr, hsz = size * hr;
    double bx2 = rint(wsz * 0.5), by2 = rint(hsz * 0.5);
    double bx1 = rint(-(wsz * 0.5)), by1 = rint(-(hsz * 0.5));
    double sx = (double)(px * d_stridec[lvl]), sy = (double)(py * d_stridec[lvl]);
    double x1 = sx + bx1, yy1 = sy + by1;
    double x2 = sx + bx2, yy2 = sy + by2;
    double pw = x2 - x1, ph = yy2 - yy1;
    double pcx = x1 + 0.5 * pw, pcy = yy1 + 0.5 * ph;
    double cx = dx * pw + pcx, cy = dy * ph + pcy;
    double w = exp(dw) * pw, h = exp(dh) * ph;
    X1 = fmin(fmax(cx - 0.5 * w, 0.0), 1216.0);
    Y1 = fmin(fmax(cy - 0.5 * h, 0.0), 800.0);
    X2 = fmin(fmax(cx + 0.5 * w, 0.0), 1216.0);
    Y2 = fmin(fmax(cy + 0.5 * h, 0.0), 800.0);
    sc = ((X2 - X1) > 0.001 && (Y2 - Y1) > 0.001) ? s : -1.0;
  }
  double* bp = boxes + (size_t)(bl * 1000 + rank) * 4;
  bp[0] = X1; bp[1] = Y1; bp[2] = X2; bp[3] = Y2;
  sc0[bl * 1000 + rank] = sc;
}

__global__ __launch_bounds__(256) void nms_mask_k(const double* __restrict__ boxes,
                                                  u64* __restrict__ gmask) {
  int blk = blockIdx.x;
  int bl = blk >> 2, qt = blk & 3;
  __shared__ double X1[1000], Y1[1000], X2[1000], Y2[1000], AR[1000];
  int t = threadIdx.x;
  for (int i = t; i < 1000; i += 256) {
    const double* bp = boxes + (size_t)(bl * 1000 + i) * 4;
    double x1 = bp[0], y1 = bp[1], x2 = bp[2], y2 = bp[3];
    X1[i] = x1; Y1[i] = y1; X2[i] = x2; Y2[i] = y2;
    AR[i] = (x2 - x1) * (y2 - y1);
  }
  __syncthreads();
  if (t < 250) {
    int i = qt * 250 + t;
    double ax1 = X1[i], ay1 = Y1[i], ax2 = X2[i], ay2 = Y2[i], aa = AR[i];
    u64* gm = gmask + (size_t)bl * 16000 + (size_t)i * 16;
    for (int wj = 0; wj < 16; ++wj) {
      u64 bits = 0;
      int jb0 = wj * 64;
      for (int jb = 0; jb < 64; ++jb) {
        int j = jb0 + jb;
        if (j <= i || j >= 1000) continue;
        double lx = fmax(ax1, X1[j]), ly = fmax(ay1, Y1[j]);
        double rx = fmin(ax2, X2[j]), ry = fmin(ay2, Y2[j]);
        double ww = fmax(rx - lx, 0.0), hh = fmax(ry - ly, 0.0);
        double inter = ww * hh;
        double uni = (aa + AR[j]) - inter;
        double iou = inter / fmax(uni, 1e-9);
        if (iou > 0.7) bits |= (1ull << jb);
      }
      gm[wj] = bits;
    }
  }
}

__global__ void nms_scan_k(double* __restrict__ sc0, const u64* __restrict__ gmask) {
  int bl = blockIdx.x;
  int lane = threadIdx.x;
  const u64* gm = gmask + (size_t)bl * 16000;
  u64 keepw = 0;
  if (lane < 16) {
    for (int jb = 0; jb < 64; ++jb) {
      int j = lane * 64 + jb;
      if (j < 1000 && sc0[bl * 1000 + j] > -0.5) keepw |= (1ull << jb);
    }
  }
  u64 m0 = 0, m1 = 0, m2 = 0, m3 = 0;
  if (lane < 16) {
    m0 = gm[0 * 16 + lane]; m1 = gm[1 * 16 + lane];
    m2 = gm[2 * 16 + lane]; m3 = gm[3 * 16 + lane];
  }
  for (int i = 0; i < 1000; i += 4) {
    u64 n0 = 0, n1 = 0, n2 = 0, n3 = 0;
    if (lane < 16 && i + 4 < 1000) {
      n0 = gm[(i + 4) * 16 + lane]; n1 = gm[(i + 5) * 16 + lane];
      n2 = gm[(i + 6) * 16 + lane]; n3 = gm[(i + 7) * 16 + lane];
    }
    { u64 kw = __shfl(keepw, (i    ) >> 6); if ((kw >> ((i    ) & 63)) & 1) { if (lane < 16) keepw &= ~m0; } }
    { u64 kw = __shfl(keepw, (i + 1) >> 6); if ((kw >> ((i + 1) & 63)) & 1) { if (lane < 16) keepw &= ~m1; } }
    { u64 kw = __shfl(keepw, (i + 2) >> 6); if ((kw >> ((i + 2) & 63)) & 1) { if (lane < 16) keepw &= ~m2; } }
    { u64 kw = __shfl(keepw, (i + 3) >> 6); if ((kw >> ((i + 3) & 63)) & 1) { if (lane < 16) keepw &= ~m3; } }
    m0 = n0; m1 = n1; m2 = n2; m3 = n3;
  }
  if (lane < 16) {
    for (int jb = 0; jb < 64; ++jb) {
      int j = lane * 64 + jb;
      if (j < 1000) {
        double ss = sc0[bl * 1000 + j];
        sc0[bl * 1000 + j] = ((keepw >> jb) & 1) ? ss : -1.0;
      }
    }
  }
}

__global__ __launch_bounds__(1024) void final_k(const double* __restrict__ sc0,
                                                const double* __restrict__ boxes,
                                                float* __restrict__ out) {
  int b = blockIdx.x;
  __shared__ u64 s[8192];
  for (int i = threadIdx.x; i < 8192; i += 1024) {
    u64 v = 0;
    if (i < 5000) {
      u64 k = d2k(sc0[b * 5000 + i]);
      v = ((k >> 18) << 18) | (u64)(0x3FFFFu - (u32)i);
    }
    s[i] = v;
  }
  __syncthreads();
  bitonic8192_desc(s);
  for (int r = threadIdx.x; r < 1000; r += 1024) {
    u64 v = s[r];
    int idx = (int)(0x3FFFFu - (u32)(v & 0x3FFFFu));
    double score = sc0[b * 5000 + idx];
    const double* bp = boxes + (size_t)(b * 5000 + idx) * 4;
    float* op = out + ((size_t)b * 1000 + r) * 5;
    op[0] = (float)bp[0]; op[1] = (float)bp[1];
    op[2] = (float)bp[2]; op[3] = (float)bp[3];
    op[4] = (float)score;
  }
}

// ---------------- host ----------------
extern "C" void kernel_launch(void* const* d_in, const int* in_sizes, int n_in,
                              void* d_out, int out_size, void* d_ws, size_t ws_size,
                              hipStream_t stream) {
  const float* p[5];
  for (int i = 0; i < 5; ++i) p[i] = (const float*)d_in[i];
  const float* conv_w = (const float*)d_in[5];
  const float* conv_b = (const float*)d_in[6];
  const float* cls_w  = (const float*)d_in[7];
  const float* cls_b  = (const float*)d_in[8];
  const float* reg_w  = (const float*)d_in[9];
  const float* reg_b  = (const float*)d_in[10];
  float* out = (float*)d_out;

  char* ws = (char*)d_ws;
  size_t off = 0;
  auto alloc = [&](size_t bytes) -> void* {
    void* pt = ws + off;
    off = (off + bytes + 255) & ~(size_t)255;
    return pt;
  };
  const size_t XTB = (size_t)2 * PXPAD * 256 * 2 + 65536;     // 85.0 MB (padded bf16 hi)
  float*  wt       = (float*) alloc(2304ull * 256 * 4);       // 2.36 MB (rescore)
  short*  wbh      = (short*) alloc(73728ull * 8 * 2);        // 1.18 MB
  short*  wbl      = (short*) alloc(73728ull * 8 * 2);        // 1.18 MB
  short*  xh       = (short*) alloc(XTB);                     // 85 MB
  float*  scr32    = (float*) alloc(2ull * ATOT * 4);         // 1.94 MB
  double* scr64    = (double*)alloc(2ull * ATOT * 8);         // 3.89 MB
  double* reg64    = (double*)alloc(2ull * ATOT * 4 * 8);     // 15.55 MB
  u32*    hist     = (u32*)   alloc(10ull * 65536 * 4);       // 2.62 MB
  int*    meta     = (int*)   alloc(10ull * 8 * 4);
  u32*    complist = (u32*)   alloc(10ull * 8192 * 4);
  u64*    comp64   = (u64*)   alloc(10ull * 8192 * 8);
  u8*     flags    = (u8*)    alloc(2ull * PXTOT);
  u32*    worklist = (u32*)   alloc(65536ull * 4);
  int*    wlcount  = (int*)   alloc(256);
  int*    topidx   = (int*)   alloc(10ull * 1000 * 4);
  double* boxes    = (double*)alloc(2ull * 5000 * 4 * 8);
  double* sc0      = (double*)alloc(2ull * 5000 * 8);
  u64*    gmask    = (u64*)   alloc(10ull * 1000 * 16 * 8);

  wtrans_k<<<(2304 * 256 + 255) / 256, 256, 0, stream>>>(conv_w, wt);
  wcvt_k<<<288, 256, 0, stream>>>(conv_w, wbh, wbl);
  hipMemsetAsync(xh, 0, XTB, stream);
  xcvt_k<<<5064, 256, 0, stream>>>(p[0], p[1], p[2], p[3], p[4], xh);
  conv_mfma_k<<<1440, 256, 0, stream>>>(xh, wbh, wbl, conv_b, cls_w, cls_b, scr32);

  int nblk = (2 * ATOT + 255) / 256;
  hipMemsetAsync(hist, 0, 10ull * 65536 * 4, stream);
  hist_hi_k<<<nblk, 256, 0, stream>>>(scr32, hist);
  scan_hi_k<<<10, 256, 0, stream>>>(hist, meta);
  hipMemsetAsync(hist, 0, 10ull * 65536 * 4, stream);
  hist_lo_k<<<nblk, 256, 0, stream>>>(scr32, meta, hist);
  scan_lo_k<<<10, 256, 0, stream>>>(hist, meta);

  hipMemsetAsync(flags, 0, 2ull * PXTOT, stream);
  hipMemsetAsync(wlcount, 0, 4, stream);
  compact_k<<<nblk, 256, 0, stream>>>(scr32, meta, complist, flags);
  pxcompact_k<<<(2 * PXTOT + 255) / 256, 256, 0, stream>>>(flags, worklist, wlcount);

  rescore_k<<<RSG, 256, 0, stream>>>(p[0], p[1], p[2], p[3], p[4],
                                     wt, conv_b, cls_w, cls_b, reg_w, reg_b,
                                     worklist, wlcount, scr64, reg64);

  buildkeys_k<<<10, 256, 0, stream>>>(complist, meta, scr64, comp64);
  sort_level_k<<<10, 1024, 0, stream>>>(comp64, meta, topidx);
  decode_k<<<40, 256, 0, stream>>>(topidx, scr64, reg64, boxes, sc0);
  nms_mask_k<<<40, 256, 0, stream>>>(boxes, gmask);
  nms_scan_k<<<10, 64, 0, stream>>>(sc0, gmask);
  final_k<<<2, 1024, 0, stream>>>(sc0, boxes, out);
}

// Round 8
// 2159.948 us; speedup vs baseline: 1.8599x; 1.0744x over previous
//
#include <hip/hip_runtime.h>
#include <stdint.h>
#include <math.h>

typedef unsigned long long u64;
typedef unsigned int u32;
typedef unsigned char u8;
typedef short s16x8 __attribute__((ext_vector_type(8)));
typedef float f32x4 __attribute__((ext_vector_type(4)));

#define ATOT 242991    // total anchors per batch
#define PXTOT 80997    // total pixels per batch
#define PXPAD 82971    // padded (H+2)x(W+2) pixels per batch

__device__ __constant__ int    d_Hs[5]      = {200,100,50,25,13};
__device__ __constant__ int    d_Ws[5]      = {304,152,76,38,19};
__device__ __constant__ int    d_Wp[5]      = {306,154,78,40,21};
__device__ __constant__ int    d_stridec[5] = {4,8,16,32,64};
__device__ __constant__ double d_sized[5]   = {32.0,64.0,128.0,256.0,512.0};
__device__ __constant__ int    d_off[5]     = {0,182400,228000,239400,242250};
__device__ __constant__ int    d_pxoff[6]   = {0,60800,76000,79800,80750,80997};
__device__ __constant__ int    d_poff[5]    = {0,61812,77520,81576,82656};
__device__ __constant__ int    d_Ncand[5]   = {182400,45600,11400,2850,741};
// xcvt: 32-px chunks per level {1900,475,119,30,8} -> 2532/batch
__device__ __constant__ int    d_xcb[5]     = {0,1900,2375,2494,2524};
// conv: single-row 64-px tiles: {1000,300,100,25,13} = 1438/batch
__device__ __constant__ int    d_ctb[5]     = {0,1000,1300,1400,1425};
__device__ __constant__ int    d_tX[5]      = {5,3,2,1,1};

__device__ __forceinline__ u32 f2k32(float f) {
  u32 u = __float_as_uint(f);
  return (u & 0x80000000u) ? ~u : (u | 0x80000000u);
}
__device__ __forceinline__ float k2f32(u32 k) {
  u32 u = (k & 0x80000000u) ? (k & 0x7FFFFFFFu) : ~k;
  return __uint_as_float(u);
}
__device__ __forceinline__ u64 d2k(double d) {
  u64 b = (u64)__double_as_longlong(d);
  return (b & 0x8000000000000000ull) ? ~b : (b | 0x8000000000000000ull);
}
__device__ __forceinline__ unsigned short f2bf(float v) {   // RNE (weights only)
  u32 b = __float_as_uint(v);
  return (unsigned short)((b + 0x7FFFu + ((b >> 16) & 1u)) >> 16);
}
__device__ __forceinline__ float bf2f(unsigned short h) {
  return __uint_as_float(((u32)h) << 16);
}

// ---------------- weight transpose for rescore: w[oc][ic][3][3] -> wt[ic][tap][oc] ----
__global__ void wtrans_k(const float* __restrict__ w, float* __restrict__ wt) {
  int gid = blockIdx.x * 256 + threadIdx.x;
  if (gid >= 2304 * 256) return;
  int oc = gid & 255;
  int rest = gid >> 8;
  int ic = rest / 9, tap = rest % 9;
  wt[gid] = w[(oc * 256 + ic) * 9 + tap];
}

// ---------------- weight -> B-fragment swizzle (bf16 hi/lo, RNE) ----------------
__global__ void wcvt_k(const float* __restrict__ w, short* __restrict__ wbh,
                       short* __restrict__ wbl) {
  int gid = blockIdx.x * 256 + threadIdx.x;   // 73728 = 9*8*16*64
  if (gid >= 73728) return;
  int lane = gid & 63;
  int rest = gid >> 6;                         // (tap*8+slice)*16 + oct
  int oct = rest & 15, rs = rest >> 4;
  int slice = rs & 7, tap = rs >> 3;
  int oc = oct * 16 + (lane & 15);
  int icb = slice * 32 + (lane >> 4) * 8;
  size_t ob = (size_t)gid * 8;
#pragma unroll
  for (int j = 0; j < 8; ++j) {
    float v = w[(oc * 256 + icb + j) * 9 + tap];
    unsigned short h = f2bf(v);
    wbh[ob + j] = (short)h;
    wbl[ob + j] = (short)f2bf(v - bf2f(h));
  }
}

// ---------------- x NCHW fp32 -> NHWC-padded BITWISE split (hi=top16, lo=bottom16) ----
// xh doubles as truncated-bf16 for the MFMA screen; (xh<<16)|xl reconstructs fp32 EXACTLY.
__global__ __launch_bounds__(256) void xcvt_k(
    const float* __restrict__ x0, const float* __restrict__ x1,
    const float* __restrict__ x2, const float* __restrict__ x3,
    const float* __restrict__ x4, short* __restrict__ xh, short* __restrict__ xl)
{
  __shared__ float tile[32 * 257];
  const int bid = blockIdx.x;
  const int b = bid / 2532;
  int r = bid % 2532;
  int lvl = 0;
#pragma unroll
  for (int l2 = 1; l2 < 5; ++l2) if (r >= d_xcb[l2]) lvl = l2;
  const int chunk = r - d_xcb[lvl];
  const int H = d_Hs[lvl], W = d_Ws[lvl], HW = H * W, Wp = d_Wp[lvl];
  const int px0 = chunk * 32;
  const float* xs[5] = {x0, x1, x2, x3, x4};
  const float* xb = xs[lvl] + (size_t)b * 256 * HW;
  const int t = threadIdx.x;

  for (int icg = 0; icg < 32; ++icg) {
    int ic = icg * 8 + (t >> 5);
    int px = px0 + (t & 31);
    float v = (px < HW) ? xb[(size_t)ic * HW + px] : 0.f;
    tile[(t & 31) * 257 + ic] = v;
  }
  __syncthreads();
  int px = t >> 3;
  int gpx = px0 + px;
  if (gpx < HW) {
    int yy = gpx / W, xx = gpx % W;
    size_t obase = ((size_t)(b * PXPAD + d_poff[lvl]) +
                    (size_t)(yy + 1) * Wp + (xx + 1)) * 256 + (size_t)(t & 7) * 32;
#pragma unroll
    for (int q = 0; q < 4; ++q) {
      s16x8 hi, lo;
#pragma unroll
      for (int j = 0; j < 8; ++j) {
        u32 bits = __float_as_uint(tile[px * 257 + (t & 7) * 32 + q * 8 + j]);
        hi[j] = (short)(bits >> 16);       // truncated bf16 (screen operand)
        lo[j] = (short)(bits & 0xFFFFu);   // exact low bits (rescore reconstruct)
      }
      *(s16x8*)(xh + obase + q * 8) = hi;
      *(s16x8*)(xl + obase + q * 8) = lo;
    }
  }
}

// ---------------- 2-term split-bf16 MFMA conv3x3 + ReLU + in-register cls screen -----
// block = 4 waves; tile = 1 row x 64 px x 256 oc; wave -> 64 oc.
// acc = 64 regs -> ~144 total/thread -> 3 waves/SIMD.
__global__ __launch_bounds__(256) void conv_mfma_k(
    const short* __restrict__ xh,
    const short* __restrict__ wbh, const short* __restrict__ wbl,
    const float* __restrict__ convb, const float* __restrict__ clsw,
    const float* __restrict__ clsb, float* __restrict__ scr32)
{
  __shared__ float zl[4][64][3];
  const int bid = blockIdx.x;
  const int b = bid / 1438;
  int r = bid % 1438;
  int lvl = 0;
#pragma unroll
  for (int l2 = 1; l2 < 5; ++l2) if (r >= d_ctb[l2]) lvl = l2;
  const int lid = r - d_ctb[lvl];
  const int tX = d_tX[lvl];
  const int y = lid / tX, x0 = (lid % tX) * 64;
  const int W = d_Ws[lvl], Wp = d_Wp[lvl];
  const size_t pbase = (size_t)(b * PXPAD + d_poff[lvl]);

  const int t = threadIdx.x;
  const int lane = t & 63;
  const int wid = t >> 6;
  const int aoff = (lane & 15) * 256 + (lane >> 4) * 8;

  f32x4 acc[4][4];
#pragma unroll
  for (int m = 0; m < 4; ++m)
#pragma unroll
    for (int o = 0; o < 4; ++o) acc[m][o] = (f32x4){0.f, 0.f, 0.f, 0.f};

#pragma unroll 1
  for (int tap = 0; tap < 9; ++tap) {
    const int ky = tap / 3, kx = tap % 3;
    const size_t re = (pbase + (size_t)(y + ky) * Wp + (x0 + kx)) * 256;
    const short* pa = xh + re;
    const short* pbh = wbh + (size_t)tap * 8 * 16 * 512;
    const short* pbl = wbl + (size_t)tap * 8 * 16 * 512;
#pragma unroll 1
    for (int slice = 0; slice < 8; ++slice) {
      s16x8 bh[4], bl4[4], a[4];
#pragma unroll
      for (int o = 0; o < 4; ++o) {
        size_t bo = ((size_t)(slice * 16 + wid * 4 + o) * 64 + lane) * 8;
        bh[o]  = *(const s16x8*)(pbh + bo);
        bl4[o] = *(const s16x8*)(pbl + bo);
      }
#pragma unroll
      for (int m = 0; m < 4; ++m) {
        size_t ao = (size_t)aoff + slice * 32 + m * 4096;
        a[m] = *(const s16x8*)(pa + ao);
      }
#pragma unroll
      for (int m = 0; m < 4; ++m)
#pragma unroll
        for (int o = 0; o < 4; ++o) {
          acc[m][o] = __builtin_amdgcn_mfma_f32_16x16x32_bf16(a[m], bh[o],  acc[m][o], 0, 0, 0);
          acc[m][o] = __builtin_amdgcn_mfma_f32_16x16x32_bf16(a[m], bl4[o], acc[m][o], 0, 0, 0);
        }
    }
  }

  // epilogue: bias + relu + cls partial over this wave's 64 oc, reduce over 16 lanes
  float bb[4], cw0[4], cw1[4], cw2[4];
#pragma unroll
  for (int o = 0; o < 4; ++o) {
    int oc = wid * 64 + o * 16 + (lane & 15);
    bb[o]  = convb[oc];
    cw0[o] = clsw[0 * 256 + oc];
    cw1[o] = clsw[1 * 256 + oc];
    cw2[o] = clsw[2 * 256 + oc];
  }
#pragma unroll
  for (int m = 0; m < 4; ++m) {
#pragma unroll
    for (int q = 0; q < 4; ++q) {
      float h0 = fmaxf(acc[m][0][q] + bb[0], 0.f);
      float h1 = fmaxf(acc[m][1][q] + bb[1], 0.f);
      float h2 = fmaxf(acc[m][2][q] + bb[2], 0.f);
      float h3 = fmaxf(acc[m][3][q] + bb[3], 0.f);
      float z0 = fmaf(h0, cw0[0], fmaf(h1, cw0[1], fmaf(h2, cw0[2], h3 * cw0[3])));
      float z1 = fmaf(h0, cw1[0], fmaf(h1, cw1[1], fmaf(h2, cw1[2], h3 * cw1[3])));
      float z2 = fmaf(h0, cw2[0], fmaf(h1, cw2[1], fmaf(h2, cw2[2], h3 * cw2[3])));
      z0 += __shfl_xor(z0, 1); z0 += __shfl_xor(z0, 2); z0 += __shfl_xor(z0, 4); z0 += __shfl_xor(z0, 8);
      z1 += __shfl_xor(z1, 1); z1 += __shfl_xor(z1, 2); z1 += __shfl_xor(z1, 4); z1 += __shfl_xor(z1, 8);
      z2 += __shfl_xor(z2, 1); z2 += __shfl_xor(z2, 2); z2 += __shfl_xor(z2, 4); z2 += __shfl_xor(z2, 8);
      if ((lane & 15) == 0) {
        int slot = m * 16 + (lane >> 4) * 4 + q;
        zl[wid][slot][0] = z0; zl[wid][slot][1] = z1; zl[wid][slot][2] = z2;
      }
    }
  }
  __syncthreads();
  if (t < 192) {
    int slot = t / 3, head = t % 3;
    int col = x0 + slot;
    if (col < W) {
      float z = zl[0][slot][head] + zl[1][slot][head] + zl[2][slot][head] +
                zl[3][slot][head] + clsb[head];
      int pix = y * W + col;
      scr32[(size_t)b * ATOT + d_off[lvl] + (size_t)pix * 3 + head] =
          1.f / (1.f + expf(-z));
    }
  }
}

// ---------------- PHASE B: fp32 radix select with safety margin ----------------
__device__ __forceinline__ void locate(int gid, int& b, int& r, int& lvl) {
  b = gid / ATOT; r = gid % ATOT;
  lvl = (r < 182400) ? 0 : (r < 228000) ? 1 : (r < 239400) ? 2 : (r < 242250) ? 3 : 4;
}

__global__ void hist_hi_k(const float* __restrict__ scr, u32* __restrict__ hist) {
  int gid = blockIdx.x * 256 + threadIdx.x;
  if (gid >= 2 * ATOT) return;
  int b, r, lvl; locate(gid, b, r, lvl);
  u32 key = f2k32(scr[gid]);
  atomicAdd(&hist[((b * 5 + lvl) << 16) + (key >> 16)], 1u);
}

__global__ void scan_hi_k(const u32* __restrict__ hist, int* __restrict__ meta) {
  int bl = blockIdx.x, lvl = bl % 5;
  u32 k_sel = (u32)min(1000, d_Ncand[lvl]);
  const u32* h = hist + ((size_t)bl << 16);
  __shared__ u32 part[256];
  __shared__ u32 row[256];
  __shared__ int csel;
  __shared__ u32 cumsh;
  int t = threadIdx.x;
  u32 s = 0;
  for (int v = 0; v < 256; ++v) s += h[t * 256 + v];
  part[t] = s;
  __syncthreads();
  if (t == 0) {
    u32 cum = 0; int c = 255;
    for (; c > 0; --c) { if (cum + part[c] >= k_sel) break; cum += part[c]; }
    csel = c; cumsh = cum;
  }
  __syncthreads();
  row[t] = h[csel * 256 + t];      // coalesced stage of the selected bin-row
  __syncthreads();
  if (t == 0) {
    u32 cum = cumsh;
    int pivot = csel * 256;
    for (int v = 255; v >= 0; --v) {
      if (cum + row[v] >= k_sel) { pivot = csel * 256 + v; break; }
      cum += row[v];
    }
    meta[bl * 8 + 0] = pivot;
    meta[bl * 8 + 1] = (int)cum;
  }
}

__global__ void hist_lo_k(const float* __restrict__ scr, const int* __restrict__ meta,
                          u32* __restrict__ hist) {
  int gid = blockIdx.x * 256 + threadIdx.x;
  if (gid >= 2 * ATOT) return;
  int b, r, lvl; locate(gid, b, r, lvl);
  int bl = b * 5 + lvl;
  u32 key = f2k32(scr[gid]);
  if ((int)(key >> 16) == meta[bl * 8 + 0])
    atomicAdd(&hist[(bl << 16) + (key & 0xFFFFu)], 1u);
}

__global__ void scan_lo_k(const u32* __restrict__ hist, int* __restrict__ meta) {
  int bl = blockIdx.x, lvl = bl % 5;
  u32 k_sel = (u32)min(1000, d_Ncand[lvl]);
  const u32* h = hist + ((size_t)bl << 16);
  __shared__ u32 part[256];
  __shared__ u32 row[256];
  __shared__ int csel;
  __shared__ u32 cumsh;
  int t = threadIdx.x;
  u32 s = 0;
  for (int v = 0; v < 256; ++v) s += h[t * 256 + v];
  part[t] = s;
  __syncthreads();
  if (t == 0) {
    u32 cum = (u32)meta[bl * 8 + 1];
    int c = 255;
    for (; c > 0; --c) { if (cum + part[c] >= k_sel) break; cum += part[c]; }
    csel = c; cumsh = cum;
  }
  __syncthreads();
  row[t] = h[csel * 256 + t];
  __syncthreads();
  if (t == 0) {
    u32 cum = cumsh;
    int pivot = csel * 256;
    for (int v = 255; v >= 0; --v) {
      if (cum + row[v] >= k_sel) { pivot = csel * 256 + v; break; }
      cum += row[v];
    }
    u32 P = (((u32)meta[bl * 8 + 0]) << 16) | (u32)pivot;   // exact fp32 kth key
    u32 T = f2k32(k2f32(P) - 5e-3f);                        // margin covers 2-term err
    if (d_Ncand[lvl] <= 1000) T = 0;                        // keep all
    meta[bl * 8 + 2] = (int)T;
    meta[bl * 8 + 4] = 0;   // compact counter
  }
}

__global__ void compact_k(const float* __restrict__ scr, int* __restrict__ meta,
                          u32* __restrict__ complist, u8* __restrict__ flags) {
  int gid = blockIdx.x * 256 + threadIdx.x;
  if (gid >= 2 * ATOT) return;
  int b, r, lvl; locate(gid, b, r, lvl);
  int bl = b * 5 + lvl;
  u32 key = f2k32(scr[gid]);
  if (key >= (u32)meta[bl * 8 + 2]) {
    int pos = atomicAdd(&meta[bl * 8 + 4], 1);
    if (pos < 8192) {
      u32 li = (u32)(r - d_off[lvl]);
      complist[bl * 8192 + pos] = li;
      flags[b * PXTOT + d_pxoff[lvl] + li / 3] = 1;
    }
  }
}

__global__ void pxcompact_k(u8* __restrict__ flags, u32* __restrict__ worklist,
                            int* __restrict__ wlcount) {
  int gid = blockIdx.x * 256 + threadIdx.x;
  if (gid >= 2 * PXTOT) return;
  if (flags[gid]) {
    flags[gid] = 0;
    int pos = atomicAdd(wlcount, 1);
    if (pos < 65536) worklist[pos] = (u32)gid;
  }
}

// ---------------- PHASE C: sparse fp64 rescore of flagged pixels ----------------
// x reconstructed BIT-EXACTLY as (xh<<16)|xl; staging fully coalesced from NHWC pad.
#define RSG 2048
__global__ __launch_bounds__(256) void rescore_k(
    const short* __restrict__ xh, const short* __restrict__ xl,
    const float* __restrict__ wt, const float* __restrict__ convb,
    const float* __restrict__ clsw, const float* __restrict__ clsb,
    const float* __restrict__ regw, const float* __restrict__ regb,
    const u32* __restrict__ worklist, const int* __restrict__ wlcount,
    double* __restrict__ scr64, double* __restrict__ reg64)
{
  __shared__ float xlb[4 * 2304];   // [slot][ic*9+tap]  36.9 KB
  __shared__ double hl[4 * 256];    // 8 KB
  const int t = threadIdx.x;
  int count = *wlcount; if (count > 65536) count = 65536;

  for (int base = blockIdx.x * 4; base < count; base += RSG * 4) {
    int sb[4], slvl[4], spix[4];
    size_t pb0[4];
    bool valid[4];
#pragma unroll
    for (int s = 0; s < 4; ++s) {
      int w = base + s;
      valid[s] = (w < count);
      sb[s] = 0; slvl[s] = 0; spix[s] = 0; pb0[s] = 0;
      if (valid[s]) {
        u32 g = worklist[w];
        int b = (int)(g / PXTOT), lp = (int)(g % PXTOT);
        int lvl = 0;
#pragma unroll
        for (int l = 1; l < 5; ++l) if (lp >= d_pxoff[l]) lvl = l;
        int pix = lp - d_pxoff[lvl];
        int W = d_Ws[lvl], Wp = d_Wp[lvl];
        int py = pix / W, px = pix % W;
        sb[s] = b; slvl[s] = lvl; spix[s] = pix;
        pb0[s] = ((size_t)(b * PXPAD + d_poff[lvl]) + (size_t)py * Wp + px) * 256;
      }
    }
    __syncthreads();
#pragma unroll
    for (int s = 0; s < 4; ++s) {
      if (valid[s]) {
        int Wp = d_Wp[slvl[s]];
        for (int i = t; i < 1152; i += 256) {
          int tap = i >> 7, pair = i & 127;
          int ky = tap / 3, kx = tap % 3;
          size_t po = pb0[s] + ((size_t)ky * Wp + kx) * 256 + (size_t)pair * 2;
          u32 vh = *(const u32*)(xh + po);
          u32 vl = *(const u32*)(xl + po);
          float xa  = __uint_as_float(((vh & 0xFFFFu) << 16) | (vl & 0xFFFFu));
          float xb2 = __uint_as_float((vh & 0xFFFF0000u) | (vl >> 16));
          xlb[s * 2304 + (pair * 2) * 9 + tap] = xa;
          xlb[s * 2304 + (pair * 2 + 1) * 9 + tap] = xb2;
        }
      }
    }
    __syncthreads();
    double h[4] = {0.0, 0.0, 0.0, 0.0};
    for (int ic = 0; ic < 256; ++ic) {
      double wd[9];
#pragma unroll
      for (int tap = 0; tap < 9; ++tap)
        wd[tap] = (double)wt[(ic * 9 + tap) * 256 + t];
#pragma unroll
      for (int s = 0; s < 4; ++s) {
        const float* xp = &xlb[s * 2304 + ic * 9];
#pragma unroll
        for (int tap = 0; tap < 9; ++tap)
          h[s] = fma((double)xp[tap], wd[tap], h[s]);
      }
    }
    double bias = (double)convb[t];
#pragma unroll
    for (int s = 0; s < 4; ++s) {
      h[s] = fmax(h[s] + bias, 0.0);
      hl[s * 256 + t] = h[s];
    }
    __syncthreads();
    {
      int s = t >> 6, lane = t & 63;
      if (valid[s]) {
        int lvl = slvl[s];
        size_t g3 = (size_t)sb[s] * ATOT + d_off[lvl] + (size_t)spix[s] * 3;
        for (int head = 0; head < 15; ++head) {
          const float* hw = (head < 3) ? (clsw + head * 256) : (regw + (head - 3) * 256);
          double part = 0.0;
#pragma unroll
          for (int q = 0; q < 4; ++q) {
            int oc = lane + q * 64;
            part = fma(hl[s * 256 + oc], (double)hw[oc], part);
          }
          part += __shfl_xor(part, 32);
          part += __shfl_xor(part, 16);
          part += __shfl_xor(part, 8);
          part += __shfl_xor(part, 4);
          part += __shfl_xor(part, 2);
          part += __shfl_xor(part, 1);
          if (lane == 0) {
            double z = part + (double)((head < 3) ? clsb[head] : regb[head - 3]);
            if (head < 3) scr64[g3 + head] = 1.0 / (1.0 + exp(-z));
            else { int hh = head - 3; reg64[(g3 + (hh >> 2)) * 4 + (hh & 3)] = z; }
          }
        }
      }
    }
    __syncthreads();
  }
}

// ---------------- PHASE D: exact fp64 keys, sort, decode, NMS, final ----------------
__global__ void buildkeys_k(const u32* __restrict__ complist, const int* __restrict__ meta,
                            const double* __restrict__ scr64, u64* __restrict__ comp64) {
  int bl = blockIdx.x;
  int b = bl / 5, lvl = bl % 5;
  int M = meta[bl * 8 + 4]; if (M > 8192) M = 8192;
  for (int i = threadIdx.x; i < 8192; i += 256) {
    u64 key = 0;
    if (i < M) {
      u32 li = complist[bl * 8192 + i];
      double sc = scr64[(size_t)b * ATOT + d_off[lvl] + li];
      key = ((d2k(sc) >> 18) << 18) | (u64)(0x3FFFFu - li);
    }
    comp64[bl * 8192 + i] = key;
  }
}

__device__ void bitonic8192_desc(u64* s) {
  int t = threadIdx.x;
  for (int k = 2; k <= 8192; k <<= 1) {
    for (int j = k >> 1; j > 0; j >>= 1) {
      __syncthreads();
#pragma unroll
      for (int q = 0; q < 4; ++q) {
        int i = t + q * 1024;
        int l = (i << 1) - (i & (j - 1));
        int m = l + j;
        bool up = ((l & k) == 0);
        u64 a = s[l], bb = s[m];
        if ((a < bb) == up) { s[l] = bb; s[m] = a; }
      }
    }
  }
  __syncthreads();
}

__global__ __launch_bounds__(1024) void sort_level_k(const u64* __restrict__ comp64,
                                                     const int* __restrict__ meta,
                                                     int* __restrict__ topidx) {
  int bl = blockIdx.x, lvl = bl % 5;
  int k_sel = min(1000, d_Ncand[lvl]);
  __shared__ u64 s[8192];
  int M = meta[bl * 8 + 4]; if (M > 8192) M = 8192;
  for (int i = threadIdx.x; i < 8192; i += 1024)
    s[i] = (i < M) ? comp64[bl * 8192 + i] : 0ull;
  __syncthreads();
  bitonic8192_desc(s);
  for (int r = threadIdx.x; r < 1000; r += 1024) {
    int v = -1;
    if (r < k_sel && r < M) v = (int)(0x3FFFFu - (u32)(s[r] & 0x3FFFFu));
    topidx[bl * 1000 + r] = v;
  }
}

__global__ void decode_k(const int* __restrict__ topidx, const double* __restrict__ scr64,
                         const double* __restrict__ reg64, double* __restrict__ boxes,
                         double* __restrict__ sc0) {
  int gid = blockIdx.x * 256 + threadIdx.x;
  if (gid >= 10000) return;
  int bl = gid / 1000, rank = gid % 1000;
  int b = bl / 5, lvl = bl % 5;
  int idx = topidx[bl * 1000 + rank];
  double X1 = 0.0, Y1 = 0.0, X2 = 0.0, Y2 = 0.0, sc = -1.0;
  if (idx >= 0) {
    size_t g = (size_t)b * ATOT + d_off[lvl] + idx;
    double s = scr64[g];
    double dx = reg64[g * 4 + 0], dy = reg64[g * 4 + 1];
    const double BCLIP = 4.135166556742356;
    double dw = fmin(reg64[g * 4 + 2], BCLIP);
    double dh = fmin(reg64[g * 4 + 3], BCLIP);
    int a = idx % 3, pix = idx / 3;
    int W = d_Ws[lvl];
    int py = pix / W, px = pix % W;
    double r = (a == 0) ? 2.0 : (a == 1) ? 1.0 : 0.5;
    double hr = sqrt(r);
    double size = d_sized[lvl];
    double wsz = size / hr, hsz = size * hr;
    double bx2 = rint(wsz * 0.5), by2 = rint(hsz * 0.5);
    double bx1 = rint(-(wsz * 0.5)), by1 = rint(-(hsz * 0.5));
    double sx = (double)(px * d_stridec[lvl]), sy = (double)(py * d_stridec[lvl]);
    double x1 = sx + bx1, yy1 = sy + by1;
    double x2 = sx + bx2, yy2 = sy + by2;
    double pw = x2 - x1, ph = yy2 - yy1;
    double pcx = x1 + 0.5 * pw, pcy = yy1 + 0.5 * ph;
    double cx = dx * pw + pcx, cy = dy * ph + pcy;
    double w = exp(dw) * pw, h = exp(dh) * ph;
    X1 = fmin(fmax(cx - 0.5 * w, 0.0), 1216.0);
    Y1 = fmin(fmax(cy - 0.5 * h, 0.0), 800.0);
    X2 = fmin(fmax(cx + 0.5 * w, 0.0), 1216.0);
    Y2 = fmin(fmax(cy + 0.5 * h, 0.0), 800.0);
    sc = ((X2 - X1) > 0.001 && (Y2 - Y1) > 0.001) ? s : -1.0;
  }
  double* bp = boxes + (size_t)(bl * 1000 + rank) * 4;
  bp[0] = X1; bp[1] = Y1; bp[2] = X2; bp[3] = Y2;
  sc0[bl * 1000 + rank] = sc;
}

__global__ __launch_bounds__(256) void nms_mask_k(const double* __restrict__ boxes,
                                                  u64* __restrict__ gmask) {
  int blk = blockIdx.x;
  int bl = blk >> 2, qt = blk & 3;
  __shared__ double X1[1000], Y1[1000], X2[1000], Y2[1000], AR[1000];
  int t = threadIdx.x;
  for (int i = t; i < 1000; i += 256) {
    const double* bp = boxes + (size_t)(bl * 1000 + i) * 4;
    double x1 = bp[0], y1 = bp[1], x2 = bp[2], y2 = bp[3];
    X1[i] = x1; Y1[i] = y1; X2[i] = x2; Y2[i] = y2;
    AR[i] = (x2 - x1) * (y2 - y1);
  }
  __syncthreads();
  if (t < 250) {
    int i = qt * 250 + t;
    double ax1 = X1[i], ay1 = Y1[i], ax2 = X2[i], ay2 = Y2[i], aa = AR[i];
    u64* gm = gmask + (size_t)bl * 16000 + (size_t)i * 16;
    for (int wj = 0; wj < 16; ++wj) {
      u64 bits = 0;
      int jb0 = wj * 64;
      for (int jb = 0; jb < 64; ++jb) {
        int j = jb0 + jb;
        if (j <= i || j >= 1000) continue;
        double lx = fmax(ax1, X1[j]), ly = fmax(ay1, Y1[j]);
        double rx = fmin(ax2, X2[j]), ry = fmin(ay2, Y2[j]);
        double ww = fmax(rx - lx, 0.0), hh = fmax(ry - ly, 0.0);
        double inter = ww * hh;
        double uni = (aa + AR[j]) - inter;
        double iou = inter / fmax(uni, 1e-9);
        if (iou > 0.7) bits |= (1ull << jb);
      }
      gm[wj] = bits;
    }
  }
}

__global__ void nms_scan_k(double* __restrict__ sc0, const u64* __restrict__ gmask) {
  int bl = blockIdx.x;
  int lane = threadIdx.x;
  const u64* gm = gmask + (size_t)bl * 16000;
  u64 keepw = 0;
  if (lane < 16) {
    for (int jb = 0; jb < 64; ++jb) {
      int j = lane * 64 + jb;
      if (j < 1000 && sc0[bl * 1000 + j] > -0.5) keepw |= (1ull << jb);
    }
  }
  u64 m0 = 0, m1 = 0, m2 = 0, m3 = 0;
  if (lane < 16) {
    m0 = gm[0 * 16 + lane]; m1 = gm[1 * 16 + lane];
    m2 = gm[2 * 16 + lane]; m3 = gm[3 * 16 + lane];
  }
  for (int i = 0; i < 1000; i += 4) {
    u64 n0 = 0, n1 = 0, n2 = 0, n3 = 0;
    if (lane < 16 && i + 4 < 1000) {
      n0 = gm[(i + 4) * 16 + lane]; n1 = gm[(i + 5) * 16 + lane];
      n2 = gm[(i + 6) * 16 + lane]; n3 = gm[(i + 7) * 16 + lane];
    }
    { u64 kw = __shfl(keepw, (i    ) >> 6); if ((kw >> ((i    ) & 63)) & 1) { if (lane < 16) keepw &= ~m0; } }
    { u64 kw = __shfl(keepw, (i + 1) >> 6); if ((kw >> ((i + 1) & 63)) & 1) { if (lane < 16) keepw &= ~m1; } }
    { u64 kw = __shfl(keepw, (i + 2) >> 6); if ((kw >> ((i + 2) & 63)) & 1) { if (lane < 16) keepw &= ~m2; } }
    { u64 kw = __shfl(keepw, (i + 3) >> 6); if ((kw >> ((i + 3) & 63)) & 1) { if (lane < 16) keepw &= ~m3; } }
    m0 = n0; m1 = n1; m2 = n2; m3 = n3;
  }
  if (lane < 16) {
    for (int jb = 0; jb < 64; ++jb) {
      int j = lane * 64 + jb;
      if (j < 1000) {
        double ss = sc0[bl * 1000 + j];
        sc0[bl * 1000 + j] = ((keepw >> jb) & 1) ? ss : -1.0;
      }
    }
  }
}

__global__ __launch_bounds__(1024) void final_k(const double* __restrict__ sc0,
                                                const double* __restrict__ boxes,
                                                float* __restrict__ out) {
  int b = blockIdx.x;
  __shared__ u64 s[8192];
  for (int i = threadIdx.x; i < 8192; i += 1024) {
    u64 v = 0;
    if (i < 5000) {
      u64 k = d2k(sc0[b * 5000 + i]);
      v = ((k >> 18) << 18) | (u64)(0x3FFFFu - (u32)i);
    }
    s[i] = v;
  }
  __syncthreads();
  bitonic8192_desc(s);
  for (int r = threadIdx.x; r < 1000; r += 1024) {
    u64 v = s[r];
    int idx = (int)(0x3FFFFu - (u32)(v & 0x3FFFFu));
    double score = sc0[b * 5000 + idx];
    const double* bp = boxes + (size_t)(b * 5000 + idx) * 4;
    float* op = out + ((size_t)b * 1000 + r) * 5;
    op[0] = (float)bp[0]; op[1] = (float)bp[1];
    op[2] = (float)bp[2]; op[3] = (float)bp[3];
    op[4] = (float)score;
  }
}

// ---------------- host ----------------
extern "C" void kernel_launch(void* const* d_in, const int* in_sizes, int n_in,
                              void* d_out, int out_size, void* d_ws, size_t ws_size,
                              hipStream_t stream) {
  const float* p[5];
  for (int i = 0; i < 5; ++i) p[i] = (const float*)d_in[i];
  const float* conv_w = (const float*)d_in[5];
  const float* conv_b = (const float*)d_in[6];
  const float* cls_w  = (const float*)d_in[7];
  const float* cls_b  = (const float*)d_in[8];
  const float* reg_w  = (const float*)d_in[9];
  const float* reg_b  = (const float*)d_in[10];
  float* out = (float*)d_out;

  char* ws = (char*)d_ws;
  size_t off = 0;
  auto alloc = [&](size_t bytes) -> void* {
    void* pt = ws + off;
    off = (off + bytes + 255) & ~(size_t)255;
    return pt;
  };
  const size_t XTB = (size_t)2 * PXPAD * 256 * 2 + 65536;     // 85.0 MB per array
  float*  wt       = (float*) alloc(2304ull * 256 * 4);       // 2.36 MB (rescore)
  short*  wbh      = (short*) alloc(73728ull * 8 * 2);        // 1.18 MB
  short*  wbl      = (short*) alloc(73728ull * 8 * 2);        // 1.18 MB
  short*  xh       = (short*) alloc(XTB);                     // 85 MB
  short*  xl       = (short*) alloc(XTB);                     // 85 MB
  float*  scr32    = (float*) alloc(2ull * ATOT * 4);         // 1.94 MB
  double* scr64    = (double*)alloc(2ull * ATOT * 8);         // 3.89 MB
  double* reg64    = (double*)alloc(2ull * ATOT * 4 * 8);     // 15.55 MB
  u32*    hist     = (u32*)   alloc(10ull * 65536 * 4);       // 2.62 MB
  int*    meta     = (int*)   alloc(10ull * 8 * 4);
  u32*    complist = (u32*)   alloc(10ull * 8192 * 4);
  u64*    comp64   = (u64*)   alloc(10ull * 8192 * 8);
  u8*     flags    = (u8*)    alloc(2ull * PXTOT);
  u32*    worklist = (u32*)   alloc(65536ull * 4);
  int*    wlcount  = (int*)   alloc(256);
  int*    topidx   = (int*)   alloc(10ull * 1000 * 4);
  double* boxes    = (double*)alloc(2ull * 5000 * 4 * 8);
  double* sc0      = (double*)alloc(2ull * 5000 * 8);
  u64*    gmask    = (u64*)   alloc(10ull * 1000 * 16 * 8);

  wtrans_k<<<(2304 * 256 + 255) / 256, 256, 0, stream>>>(conv_w, wt);
  wcvt_k<<<288, 256, 0, stream>>>(conv_w, wbh, wbl);
  hipMemsetAsync(xh, 0, XTB, stream);
  hipMemsetAsync(xl, 0, XTB, stream);
  xcvt_k<<<5064, 256, 0, stream>>>(p[0], p[1], p[2], p[3], p[4], xh, xl);
  conv_mfma_k<<<2876, 256, 0, stream>>>(xh, wbh, wbl, conv_b, cls_w, cls_b, scr32);

  int nblk = (2 * ATOT + 255) / 256;
  hipMemsetAsync(hist, 0, 10ull * 65536 * 4, stream);
  hist_hi_k<<<nblk, 256, 0, stream>>>(scr32, hist);
  scan_hi_k<<<10, 256, 0, stream>>>(hist, meta);
  hipMemsetAsync(hist, 0, 10ull * 65536 * 4, stream);
  hist_lo_k<<<nblk, 256, 0, stream>>>(scr32, meta, hist);
  scan_lo_k<<<10, 256, 0, stream>>>(hist, meta);

  hipMemsetAsync(flags, 0, 2ull * PXTOT, stream);
  hipMemsetAsync(wlcount, 0, 4, stream);
  compact_k<<<nblk, 256, 0, stream>>>(scr32, meta, complist, flags);
  pxcompact_k<<<(2 * PXTOT + 255) / 256, 256, 0, stream>>>(flags, worklist, wlcount);

  rescore_k<<<RSG, 256, 0, stream>>>(xh, xl, wt, conv_b, cls_w, cls_b, reg_w, reg_b,
                                     worklist, wlcount, scr64, reg64);

  buildkeys_k<<<10, 256, 0, stream>>>(complist, meta, scr64, comp64);
  sort_level_k<<<10, 1024, 0, stream>>>(comp64, meta, topidx);
  decode_k<<<40, 256, 0, stream>>>(topidx, scr64, reg64, boxes, sc0);
  nms_mask_k<<<40, 256, 0, stream>>>(boxes, gmask);
  nms_scan_k<<<10, 64, 0, stream>>>(sc0, gmask);
  final_k<<<2, 1024, 0, stream>>>(sc0, boxes, out);
}

// Round 9
// 1868.610 us; speedup vs baseline: 2.1499x; 1.1559x over previous
//
#include <hip/hip_runtime.h>
#include <stdint.h>
#include <math.h>

typedef unsigned long long u64;
typedef unsigned int u32;
typedef unsigned char u8;
typedef short s16x8 __attribute__((ext_vector_type(8)));
typedef float f32x4 __attribute__((ext_vector_type(4)));

#define ATOT 242991    // total anchors per batch
#define PXTOT 80997    // total pixels per batch
#define PXPAD 82971    // padded (H+2)x(W+2) pixels per batch

__device__ __constant__ int    d_Hs[5]      = {200,100,50,25,13};
__device__ __constant__ int    d_Ws[5]      = {304,152,76,38,19};
__device__ __constant__ int    d_Wp[5]      = {306,154,78,40,21};
__device__ __constant__ int    d_stridec[5] = {4,8,16,32,64};
__device__ __constant__ double d_sized[5]   = {32.0,64.0,128.0,256.0,512.0};
__device__ __constant__ int    d_off[5]     = {0,182400,228000,239400,242250};
__device__ __constant__ int    d_pxoff[6]   = {0,60800,76000,79800,80750,80997};
__device__ __constant__ int    d_poff[5]    = {0,61812,77520,81576,82656};
__device__ __constant__ int    d_Ncand[5]   = {182400,45600,11400,2850,741};
// xcvt: 32-px chunks per level {1900,475,119,30,8} -> 2532/batch
__device__ __constant__ int    d_xcb[5]     = {0,1900,2375,2494,2524};
// conv: single-row 64-px tiles: {1000,300,100,25,13} = 1438/batch
__device__ __constant__ int    d_ctb[5]     = {0,1000,1300,1400,1425};
__device__ __constant__ int    d_tX[5]      = {5,3,2,1,1};
// border pixels per level: 2*(W+2)+2*H -> cumsum
__device__ __constant__ int    d_bcum[6]    = {0,1012,1520,1776,1906,1974};

__device__ __forceinline__ u32 f2k32(float f) {
  u32 u = __float_as_uint(f);
  return (u & 0x80000000u) ? ~u : (u | 0x80000000u);
}
__device__ __forceinline__ float k2f32(u32 k) {
  u32 u = (k & 0x80000000u) ? (k & 0x7FFFFFFFu) : ~k;
  return __uint_as_float(u);
}
__device__ __forceinline__ u64 d2k(double d) {
  u64 b = (u64)__double_as_longlong(d);
  return (b & 0x8000000000000000ull) ? ~b : (b | 0x8000000000000000ull);
}
__device__ __forceinline__ unsigned short f2bf(float v) {   // RNE (weights)
  u32 b = __float_as_uint(v);
  return (unsigned short)((b + 0x7FFFu + ((b >> 16) & 1u)) >> 16);
}

// ---------------- weight transpose for rescore: w[oc][ic][3][3] -> wt[ic][tap][oc] ----
__global__ void wtrans_k(const float* __restrict__ w, float* __restrict__ wt) {
  int gid = blockIdx.x * 256 + threadIdx.x;
  if (gid >= 2304 * 256) return;
  int oc = gid & 255;
  int rest = gid >> 8;
  int ic = rest / 9, tap = rest % 9;
  wt[gid] = w[(oc * 256 + ic) * 9 + tap];
}

// ---------------- weight -> B-fragment swizzle (single RNE bf16) ----------------
__global__ void wcvt_k(const float* __restrict__ w, short* __restrict__ wbh) {
  int gid = blockIdx.x * 256 + threadIdx.x;   // 73728 = 9*8*16*64
  if (gid >= 73728) return;
  int lane = gid & 63;
  int rest = gid >> 6;                         // (tap*8+slice)*16 + oct
  int oct = rest & 15, rs = rest >> 4;
  int slice = rs & 7, tap = rs >> 3;
  int oc = oct * 16 + (lane & 15);
  int icb = slice * 32 + (lane >> 4) * 8;
  size_t ob = (size_t)gid * 8;
#pragma unroll
  for (int j = 0; j < 8; ++j)
    wbh[ob + j] = (short)f2bf(w[(oc * 256 + icb + j) * 9 + tap]);
}

// ---------------- zero only the halo borders of xh/xl (replaces 170MB memsets) -------
__global__ void border_zero_k(short* __restrict__ xh, short* __restrict__ xl) {
  int tid = blockIdx.x * 256 + threadIdx.x;    // 2 batches * 1974 border px * 8 octs
  if (tid >= 2 * 1974 * 8) return;
  int oct = tid & 7;
  int rest = tid >> 3;
  int b = rest / 1974;
  int bi = rest % 1974;
  int lvl = 0;
#pragma unroll
  for (int l = 1; l < 5; ++l) if (bi >= d_bcum[l]) lvl = l;
  int li = bi - d_bcum[lvl];
  int W = d_Ws[lvl], H = d_Hs[lvl], Wp = d_Wp[lvl];
  int py, px;
  if (li < Wp)            { py = 0;     px = li; }
  else if (li < 2 * Wp)   { py = H + 1; px = li - Wp; }
  else { int rem = li - 2 * Wp; py = 1 + rem / 2; px = (rem & 1) ? (W + 1) : 0; }
  size_t base = ((size_t)(b * PXPAD + d_poff[lvl]) + (size_t)py * Wp + px) * 256
              + (size_t)oct * 32;
  s16x8 z = (s16x8){0,0,0,0,0,0,0,0};
#pragma unroll
  for (int j = 0; j < 4; ++j) {
    *(s16x8*)(xh + base + j * 8) = z;
    *(s16x8*)(xl + base + j * 8) = z;
  }
}

// ---------------- x NCHW fp32 -> NHWC-padded BITWISE split (hi=top16, lo=bottom16) ----
// coalesced stores: each 8-lane group writes a contiguous 128B channel chunk.
__global__ __launch_bounds__(256) void xcvt_k(
    const float* __restrict__ x0, const float* __restrict__ x1,
    const float* __restrict__ x2, const float* __restrict__ x3,
    const float* __restrict__ x4, short* __restrict__ xh, short* __restrict__ xl)
{
  __shared__ float tile[32 * 257];
  const int bid = blockIdx.x;
  const int b = bid / 2532;
  int r = bid % 2532;
  int lvl = 0;
#pragma unroll
  for (int l2 = 1; l2 < 5; ++l2) if (r >= d_xcb[l2]) lvl = l2;
  const int chunk = r - d_xcb[lvl];
  const int H = d_Hs[lvl], W = d_Ws[lvl], HW = H * W, Wp = d_Wp[lvl];
  const int px0 = chunk * 32;
  const float* xs[5] = {x0, x1, x2, x3, x4};
  const float* xb = xs[lvl] + (size_t)b * 256 * HW;
  const int t = threadIdx.x;

  for (int icg = 0; icg < 32; ++icg) {
    int ic = icg * 8 + (t >> 5);
    int px = px0 + (t & 31);
    float v = (px < HW) ? xb[(size_t)ic * HW + px] : 0.f;
    tile[(t & 31) * 257 + ic] = v;
  }
  __syncthreads();
  int px = t >> 3, sub = t & 7;
  int gpx = px0 + px;
  if (gpx < HW) {
    int yy = gpx / W, xx = gpx % W;
    size_t pxbase = ((size_t)(b * PXPAD + d_poff[lvl]) +
                     (size_t)(yy + 1) * Wp + (xx + 1)) * 256;
#pragma unroll
    for (int q = 0; q < 4; ++q) {
      int ch0 = q * 64 + sub * 8;
      s16x8 hi, lo;
#pragma unroll
      for (int j = 0; j < 8; ++j) {
        u32 bits = __float_as_uint(tile[px * 257 + ch0 + j]);
        hi[j] = (short)(bits >> 16);       // truncated bf16 (screen operand)
        lo[j] = (short)(bits & 0xFFFFu);   // exact low bits (rescore reconstruct)
      }
      *(s16x8*)(xh + pxbase + ch0) = hi;
      *(s16x8*)(xl + pxbase + ch0) = lo;
    }
  }
}

// ---------------- 1-term bf16 MFMA conv3x3 + ReLU + in-register cls screen ----------
// block = 4 waves; tile = 1 row x 64 px x 256 oc; wave -> 64 oc.
// B = wbh only (2.36 MB, fits per-XCD L2). acc 64 + ~64 VGPR -> 4 waves/SIMD.
__global__ __launch_bounds__(256) void conv_mfma_k(
    const short* __restrict__ xh, const short* __restrict__ wbh,
    const float* __restrict__ convb, const float* __restrict__ clsw,
    const float* __restrict__ clsb, float* __restrict__ scr32)
{
  __shared__ float zl[4][64][3];
  const int bid = blockIdx.x;
  const int b = bid / 1438;
  int r = bid % 1438;
  int lvl = 0;
#pragma unroll
  for (int l2 = 1; l2 < 5; ++l2) if (r >= d_ctb[l2]) lvl = l2;
  const int lid = r - d_ctb[lvl];
  const int tX = d_tX[lvl];
  const int y = lid / tX, x0 = (lid % tX) * 64;
  const int W = d_Ws[lvl], Wp = d_Wp[lvl];
  const size_t pbase = (size_t)(b * PXPAD + d_poff[lvl]);

  const int t = threadIdx.x;
  const int lane = t & 63;
  const int wid = t >> 6;
  const int aoff = (lane & 15) * 256 + (lane >> 4) * 8;

  f32x4 acc[4][4];
#pragma unroll
  for (int m = 0; m < 4; ++m)
#pragma unroll
    for (int o = 0; o < 4; ++o) acc[m][o] = (f32x4){0.f, 0.f, 0.f, 0.f};

#pragma unroll 1
  for (int tap = 0; tap < 9; ++tap) {
    const int ky = tap / 3, kx = tap % 3;
    const size_t re = (pbase + (size_t)(y + ky) * Wp + (x0 + kx)) * 256;
    const short* pa = xh + re;
    const short* pbh = wbh + (size_t)tap * 8 * 16 * 512;
#pragma unroll 1
    for (int slice = 0; slice < 8; ++slice) {
      s16x8 bh[4], a[4];
#pragma unroll
      for (int o = 0; o < 4; ++o) {
        size_t bo = ((size_t)(slice * 16 + wid * 4 + o) * 64 + lane) * 8;
        bh[o] = *(const s16x8*)(pbh + bo);
      }
#pragma unroll
      for (int m = 0; m < 4; ++m) {
        size_t ao = (size_t)aoff + slice * 32 + m * 4096;
        a[m] = *(const s16x8*)(pa + ao);
      }
#pragma unroll
      for (int m = 0; m < 4; ++m)
#pragma unroll
        for (int o = 0; o < 4; ++o)
          acc[m][o] = __builtin_amdgcn_mfma_f32_16x16x32_bf16(a[m], bh[o], acc[m][o], 0, 0, 0);
    }
  }

  // epilogue: bias + relu + cls partial over this wave's 64 oc, reduce over 16 lanes
  float bb[4], cw0[4], cw1[4], cw2[4];
#pragma unroll
  for (int o = 0; o < 4; ++o) {
    int oc = wid * 64 + o * 16 + (lane & 15);
    bb[o]  = convb[oc];
    cw0[o] = clsw[0 * 256 + oc];
    cw1[o] = clsw[1 * 256 + oc];
    cw2[o] = clsw[2 * 256 + oc];
  }
#pragma unroll
  for (int m = 0; m < 4; ++m) {
#pragma unroll
    for (int q = 0; q < 4; ++q) {
      float h0 = fmaxf(acc[m][0][q] + bb[0], 0.f);
      float h1 = fmaxf(acc[m][1][q] + bb[1], 0.f);
      float h2 = fmaxf(acc[m][2][q] + bb[2], 0.f);
      float h3 = fmaxf(acc[m][3][q] + bb[3], 0.f);
      float z0 = fmaf(h0, cw0[0], fmaf(h1, cw0[1], fmaf(h2, cw0[2], h3 * cw0[3])));
      float z1 = fmaf(h0, cw1[0], fmaf(h1, cw1[1], fmaf(h2, cw1[2], h3 * cw1[3])));
      float z2 = fmaf(h0, cw2[0], fmaf(h1, cw2[1], fmaf(h2, cw2[2], h3 * cw2[3])));
      z0 += __shfl_xor(z0, 1); z0 += __shfl_xor(z0, 2); z0 += __shfl_xor(z0, 4); z0 += __shfl_xor(z0, 8);
      z1 += __shfl_xor(z1, 1); z1 += __shfl_xor(z1, 2); z1 += __shfl_xor(z1, 4); z1 += __shfl_xor(z1, 8);
      z2 += __shfl_xor(z2, 1); z2 += __shfl_xor(z2, 2); z2 += __shfl_xor(z2, 4); z2 += __shfl_xor(z2, 8);
      if ((lane & 15) == 0) {
        int slot = m * 16 + (lane >> 4) * 4 + q;
        zl[wid][slot][0] = z0; zl[wid][slot][1] = z1; zl[wid][slot][2] = z2;
      }
    }
  }
  __syncthreads();
  if (t < 192) {
    int slot = t / 3, head = t % 3;
    int col = x0 + slot;
    if (col < W) {
      float z = zl[0][slot][head] + zl[1][slot][head] + zl[2][slot][head] +
                zl[3][slot][head] + clsb[head];
      int pix = y * W + col;
      scr32[(size_t)b * ATOT + d_off[lvl] + (size_t)pix * 3 + head] =
          1.f / (1.f + expf(-z));
    }
  }
}

// ---------------- PHASE B: fp32 radix select with safety margin ----------------
__device__ __forceinline__ void locate(int gid, int& b, int& r, int& lvl) {
  b = gid / ATOT; r = gid % ATOT;
  lvl = (r < 182400) ? 0 : (r < 228000) ? 1 : (r < 239400) ? 2 : (r < 242250) ? 3 : 4;
}

// hist: 4 replicas per (b,lvl) to cut hot-bin atomic serialization
__global__ void hist_hi_k(const float* __restrict__ scr, u32* __restrict__ hist) {
  int gid = blockIdx.x * 256 + threadIdx.x;
  if (gid >= 2 * ATOT) return;
  int b, r, lvl; locate(gid, b, r, lvl);
  u32 key = f2k32(scr[gid]);
  int rep = blockIdx.x & 3;
  atomicAdd(&hist[((((b * 5 + lvl) << 2) | rep) << 16) + (key >> 16)], 1u);
}

__global__ void scan_hi_k(const u32* __restrict__ hist, int* __restrict__ meta) {
  int bl = blockIdx.x, lvl = bl % 5;
  u32 k_sel = (u32)min(1000, d_Ncand[lvl]);
  const u32* h = hist + ((size_t)bl << 18);
  __shared__ u32 part[256];
  __shared__ u32 row[256];
  __shared__ int csel;
  __shared__ u32 cumsh;
  int t = threadIdx.x;
  u32 s = 0;
  for (int v = 0; v < 256; ++v) {
    int idx = t * 256 + v;
    s += h[idx] + h[65536 + idx] + h[131072 + idx] + h[196608 + idx];
  }
  part[t] = s;
  __syncthreads();
  if (t == 0) {
    u32 cum = 0; int c = 255;
    for (; c > 0; --c) { if (cum + part[c] >= k_sel) break; cum += part[c]; }
    csel = c; cumsh = cum;
  }
  __syncthreads();
  {
    int idx = csel * 256 + t;
    row[t] = h[idx] + h[65536 + idx] + h[131072 + idx] + h[196608 + idx];
  }
  __syncthreads();
  if (t == 0) {
    u32 cum = cumsh;
    int pivot = csel * 256;
    for (int v = 255; v >= 0; --v) {
      if (cum + row[v] >= k_sel) { pivot = csel * 256 + v; break; }
      cum += row[v];
    }
    meta[bl * 8 + 0] = pivot;
    meta[bl * 8 + 1] = (int)cum;
  }
}

__global__ void hist_lo_k(const float* __restrict__ scr, const int* __restrict__ meta,
                          u32* __restrict__ hist) {
  int gid = blockIdx.x * 256 + threadIdx.x;
  if (gid >= 2 * ATOT) return;
  int b, r, lvl; locate(gid, b, r, lvl);
  int bl = b * 5 + lvl;
  u32 key = f2k32(scr[gid]);
  if ((int)(key >> 16) == meta[bl * 8 + 0]) {
    int rep = blockIdx.x & 3;
    atomicAdd(&hist[(((bl << 2) | rep) << 16) + (key & 0xFFFFu)], 1u);
  }
}

__global__ void scan_lo_k(const u32* __restrict__ hist, int* __restrict__ meta) {
  int bl = blockIdx.x, lvl = bl % 5;
  u32 k_sel = (u32)min(1000, d_Ncand[lvl]);
  const u32* h = hist + ((size_t)bl << 18);
  __shared__ u32 part[256];
  __shared__ u32 row[256];
  __shared__ int csel;
  __shared__ u32 cumsh;
  int t = threadIdx.x;
  u32 s = 0;
  for (int v = 0; v < 256; ++v) {
    int idx = t * 256 + v;
    s += h[idx] + h[65536 + idx] + h[131072 + idx] + h[196608 + idx];
  }
  part[t] = s;
  __syncthreads();
  if (t == 0) {
    u32 cum = (u32)meta[bl * 8 + 1];
    int c = 255;
    for (; c > 0; --c) { if (cum + part[c] >= k_sel) break; cum += part[c]; }
    csel = c; cumsh = cum;
  }
  __syncthreads();
  {
    int idx = csel * 256 + t;
    row[t] = h[idx] + h[65536 + idx] + h[131072 + idx] + h[196608 + idx];
  }
  __syncthreads();
  if (t == 0) {
    u32 cum = cumsh;
    int pivot = csel * 256;
    for (int v = 255; v >= 0; --v) {
      if (cum + row[v] >= k_sel) { pivot = csel * 256 + v; break; }
      cum += row[v];
    }
    u32 P = (((u32)meta[bl * 8 + 0]) << 16) | (u32)pivot;   // exact fp32 kth key
    u32 T = f2k32(k2f32(P) - 5e-3f);                        // margin covers 1-term err
    if (d_Ncand[lvl] <= 1000) T = 0;                        // keep all
    meta[bl * 8 + 2] = (int)T;
    meta[bl * 8 + 4] = 0;   // compact counter
  }
}

__global__ void compact_k(const float* __restrict__ scr, int* __restrict__ meta,
                          u32* __restrict__ complist, u8* __restrict__ flags) {
  int gid = blockIdx.x * 256 + threadIdx.x;
  if (gid >= 2 * ATOT) return;
  int b, r, lvl; locate(gid, b, r, lvl);
  int bl = b * 5 + lvl;
  u32 key = f2k32(scr[gid]);
  if (key >= (u32)meta[bl * 8 + 2]) {
    int pos = atomicAdd(&meta[bl * 8 + 4], 1);
    if (pos < 8192) {
      u32 li = (u32)(r - d_off[lvl]);
      complist[bl * 8192 + pos] = li;
      flags[b * PXTOT + d_pxoff[lvl] + li / 3] = 1;
    }
  }
}

__global__ void pxcompact_k(u8* __restrict__ flags, u32* __restrict__ worklist,
                            int* __restrict__ wlcount) {
  int gid = blockIdx.x * 256 + threadIdx.x;
  if (gid >= 2 * PXTOT) return;
  if (flags[gid]) {
    flags[gid] = 0;
    int pos = atomicAdd(wlcount, 1);
    if (pos < 65536) worklist[pos] = (u32)gid;
  }
}

// ---------------- PHASE C: sparse fp64 rescore of flagged pixels ----------------
// x reconstructed BIT-EXACTLY as (xh<<16)|xl; staging fully coalesced from NHWC pad.
#define RSG 2048
__global__ __launch_bounds__(256) void rescore_k(
    const short* __restrict__ xh, const short* __restrict__ xl,
    const float* __restrict__ wt, const float* __restrict__ convb,
    const float* __restrict__ clsw, const float* __restrict__ clsb,
    const float* __restrict__ regw, const float* __restrict__ regb,
    const u32* __restrict__ worklist, const int* __restrict__ wlcount,
    double* __restrict__ scr64, double* __restrict__ reg64)
{
  __shared__ float xlb[4 * 2304];   // [slot][ic*9+tap]  36.9 KB
  __shared__ double hl[4 * 256];    // 8 KB
  const int t = threadIdx.x;
  int count = *wlcount; if (count > 65536) count = 65536;

  for (int base = blockIdx.x * 4; base < count; base += RSG * 4) {
    int sb[4], slvl[4], spix[4];
    size_t pb0[4];
    bool valid[4];
#pragma unroll
    for (int s = 0; s < 4; ++s) {
      int w = base + s;
      valid[s] = (w < count);
      sb[s] = 0; slvl[s] = 0; spix[s] = 0; pb0[s] = 0;
      if (valid[s]) {
        u32 g = worklist[w];
        int b = (int)(g / PXTOT), lp = (int)(g % PXTOT);
        int lvl = 0;
#pragma unroll
        for (int l = 1; l < 5; ++l) if (lp >= d_pxoff[l]) lvl = l;
        int pix = lp - d_pxoff[lvl];
        int W = d_Ws[lvl], Wp = d_Wp[lvl];
        int py = pix / W, px = pix % W;
        sb[s] = b; slvl[s] = lvl; spix[s] = pix;
        pb0[s] = ((size_t)(b * PXPAD + d_poff[lvl]) + (size_t)py * Wp + px) * 256;
      }
    }
    __syncthreads();
#pragma unroll
    for (int s = 0; s < 4; ++s) {
      if (valid[s]) {
        int Wp = d_Wp[slvl[s]];
        for (int i = t; i < 1152; i += 256) {
          int tap = i >> 7, pair = i & 127;
          int ky = tap / 3, kx = tap % 3;
          size_t po = pb0[s] + ((size_t)ky * Wp + kx) * 256 + (size_t)pair * 2;
          u32 vh = *(const u32*)(xh + po);
          u32 vl = *(const u32*)(xl + po);
          float xa  = __uint_as_float(((vh & 0xFFFFu) << 16) | (vl & 0xFFFFu));
          float xb2 = __uint_as_float((vh & 0xFFFF0000u) | (vl >> 16));
          xlb[s * 2304 + (pair * 2) * 9 + tap] = xa;
          xlb[s * 2304 + (pair * 2 + 1) * 9 + tap] = xb2;
        }
      }
    }
    __syncthreads();
    double h[4] = {0.0, 0.0, 0.0, 0.0};
    for (int ic = 0; ic < 256; ++ic) {
      double wd[9];
#pragma unroll
      for (int tap = 0; tap < 9; ++tap)
        wd[tap] = (double)wt[(ic * 9 + tap) * 256 + t];
#pragma unroll
      for (int s = 0; s < 4; ++s) {
        const float* xp = &xlb[s * 2304 + ic * 9];
#pragma unroll
        for (int tap = 0; tap < 9; ++tap)
          h[s] = fma((double)xp[tap], wd[tap], h[s]);
      }
    }
    double bias = (double)convb[t];
#pragma unroll
    for (int s = 0; s < 4; ++s) {
      h[s] = fmax(h[s] + bias, 0.0);
      hl[s * 256 + t] = h[s];
    }
    __syncthreads();
    {
      int s = t >> 6, lane = t & 63;
      if (valid[s]) {
        int lvl = slvl[s];
        size_t g3 = (size_t)sb[s] * ATOT + d_off[lvl] + (size_t)spix[s] * 3;
        for (int head = 0; head < 15; ++head) {
          const float* hw = (head < 3) ? (clsw + head * 256) : (regw + (head - 3) * 256);
          double part = 0.0;
#pragma unroll
          for (int q = 0; q < 4; ++q) {
            int oc = lane + q * 64;
            part = fma(hl[s * 256 + oc], (double)hw[oc], part);
          }
          part += __shfl_xor(part, 32);
          part += __shfl_xor(part, 16);
          part += __shfl_xor(part, 8);
          part += __shfl_xor(part, 4);
          part += __shfl_xor(part, 2);
          part += __shfl_xor(part, 1);
          if (lane == 0) {
            double z = part + (double)((head < 3) ? clsb[head] : regb[head - 3]);
            if (head < 3) scr64[g3 + head] = 1.0 / (1.0 + exp(-z));
            else { int hh = head - 3; reg64[(g3 + (hh >> 2)) * 4 + (hh & 3)] = z; }
          }
        }
      }
    }
    __syncthreads();
  }
}

// ---------------- PHASE D: exact fp64 keys, sort, decode, NMS, final ----------------
__global__ void buildkeys_k(const u32* __restrict__ complist, const int* __restrict__ meta,
                            const double* __restrict__ scr64, u64* __restrict__ comp64) {
  int bl = blockIdx.x;
  int b = bl / 5, lvl = bl % 5;
  int M = meta[bl * 8 + 4]; if (M > 8192) M = 8192;
  for (int i = threadIdx.x; i < 8192; i += 256) {
    u64 key = 0;
    if (i < M) {
      u32 li = complist[bl * 8192 + i];
      double sc = scr64[(size_t)b * ATOT + d_off[lvl] + li];
      key = ((d2k(sc) >> 18) << 18) | (u64)(0x3FFFFu - li);
    }
    comp64[bl * 8192 + i] = key;
  }
}

// descending bitonic sort of SZ u64 in LDS (SZ runtime: 2048 or 8192), 1024 threads
__device__ void bitonic_desc_n(u64* s, int SZ) {
  int t = threadIdx.x;
  for (int k = 2; k <= SZ; k <<= 1) {
    for (int j = k >> 1; j > 0; j >>= 1) {
      __syncthreads();
      for (int i = t; i < (SZ >> 1); i += 1024) {
        int l = (i << 1) - (i & (j - 1));
        int m = l + j;
        bool up = ((l & k) == 0);
        u64 a = s[l], bb = s[m];
        if ((a < bb) == up) { s[l] = bb; s[m] = a; }
      }
    }
  }
  __syncthreads();
}

__global__ __launch_bounds__(1024) void sort_level_k(const u64* __restrict__ comp64,
                                                     const int* __restrict__ meta,
                                                     int* __restrict__ topidx) {
  int bl = blockIdx.x, lvl = bl % 5;
  int k_sel = min(1000, d_Ncand[lvl]);
  __shared__ u64 s[8192];
  int M = meta[bl * 8 + 4]; if (M > 8192) M = 8192;
  int SZ = (M <= 2048) ? 2048 : 8192;
  for (int i = threadIdx.x; i < SZ; i += 1024)
    s[i] = (i < M) ? comp64[bl * 8192 + i] : 0ull;
  __syncthreads();
  bitonic_desc_n(s, SZ);
  for (int r = threadIdx.x; r < 1000; r += 1024) {
    int v = -1;
    if (r < k_sel && r < M) v = (int)(0x3FFFFu - (u32)(s[r] & 0x3FFFFu));
    topidx[bl * 1000 + r] = v;
  }
}

__global__ void decode_k(const int* __restrict__ topidx, const double* __restrict__ scr64,
                         const double* __restrict__ reg64, double* __restrict__ boxes,
                         double* __restrict__ sc0) {
  int gid = blockIdx.x * 256 + threadIdx.x;
  if (gid >= 10000) return;
  int bl = gid / 1000, rank = gid % 1000;
  int b = bl / 5, lvl = bl % 5;
  int idx = topidx[bl * 1000 + rank];
  double X1 = 0.0, Y1 = 0.0, X2 = 0.0, Y2 = 0.0, sc = -1.0;
  if (idx >= 0) {
    size_t g = (size_t)b * ATOT + d_off[lvl] + idx;
    double s = scr64[g];
    double dx = reg64[g * 4 + 0], dy = reg64[g * 4 + 1];
    const double BCLIP = 4.135166556742356;
    double dw = fmin(reg64[g * 4 + 2], BCLIP);
    double dh = fmin(reg64[g * 4 + 3], BCLIP);
    int a = idx % 3, pix = idx / 3;
    int W = d_Ws[lvl];
    int py = pix / W, px = pix % W;
    double r = (a == 0) ? 2.0 : (a == 1) ? 1.0 : 0.5;
    double hr = sqrt(r);
    double size = d_sized[lvl];
    double wsz = size / hr, hsz = size * hr;
    double bx2 = rint(wsz * 0.5), by2 = rint(hsz * 0.5);
    double bx1 = rint(-(wsz * 0.5)), by1 = rint(-(hsz * 0.5));
    double sx = (double)(px * d_stridec[lvl]), sy = (double)(py * d_stridec[lvl]);
    double x1 = sx + bx1, yy1 = sy + by1;
    double x2 = sx + bx2, yy2 = sy + by2;
    double pw = x2 - x1, ph = yy2 - yy1;
    double pcx = x1 + 0.5 * pw, pcy = yy1 + 0.5 * ph;
    double cx = dx * pw + pcx, cy = dy * ph + pcy;
    double w = exp(dw) * pw, h = exp(dh) * ph;
    X1 = fmin(fmax(cx - 0.5 * w, 0.0), 1216.0);
    Y1 = fmin(fmax(cy - 0.5 * h, 0.0), 800.0);
    X2 = fmin(fmax(cx + 0.5 * w, 0.0), 1216.0);
    Y2 = fmin(fmax(cy + 0.5 * h, 0.0), 800.0);
    sc = ((X2 - X1) > 0.001 && (Y2 - Y1) > 0.001) ? s : -1.0;
  }
  double* bp = boxes + (size_t)(bl * 1000 + rank) * 4;
  bp[0] = X1; bp[1] = Y1; bp[2] = X2; bp[3] = Y2;
  sc0[bl * 1000 + rank] = sc;
}

__global__ __launch_bounds__(256) void nms_mask_k(const double* __restrict__ boxes,
                                                  u64* __restrict__ gmask) {
  int blk = blockIdx.x;
  int bl = blk >> 2, qt = blk & 3;
  __shared__ double X1[1000], Y1[1000], X2[1000], Y2[1000], AR[1000];
  int t = threadIdx.x;
  for (int i = t; i < 1000; i += 256) {
    const double* bp = boxes + (size_t)(bl * 1000 + i) * 4;
    double x1 = bp[0], y1 = bp[1], x2 = bp[2], y2 = bp[3];
    X1[i] = x1; Y1[i] = y1; X2[i] = x2; Y2[i] = y2;
    AR[i] = (x2 - x1) * (y2 - y1);
  }
  __syncthreads();
  if (t < 250) {
    int i = qt * 250 + t;
    double ax1 = X1[i], ay1 = Y1[i], ax2 = X2[i], ay2 = Y2[i], aa = AR[i];
    u64* gm = gmask + (size_t)bl * 16000 + (size_t)i * 16;
    for (int wj = 0; wj < 16; ++wj) {
      u64 bits = 0;
      int jb0 = wj * 64;
      for (int jb = 0; jb < 64; ++jb) {
        int j = jb0 + jb;
        if (j <= i || j >= 1000) continue;
        double lx = fmax(ax1, X1[j]), ly = fmax(ay1, Y1[j]);
        double rx = fmin(ax2, X2[j]), ry = fmin(ay2, Y2[j]);
        double ww = fmax(rx - lx, 0.0), hh = fmax(ry - ly, 0.0);
        double inter = ww * hh;
        double uni = (aa + AR[j]) - inter;
        double iou = inter / fmax(uni, 1e-9);
        if (iou > 0.7) bits |= (1ull << jb);
      }
      gm[wj] = bits;
    }
  }
}

__global__ void nms_scan_k(double* __restrict__ sc0, const u64* __restrict__ gmask) {
  int bl = blockIdx.x;
  int lane = threadIdx.x;
  const u64* gm = gmask + (size_t)bl * 16000;
  u64 keepw = 0;
  if (lane < 16) {
    for (int jb = 0; jb < 64; ++jb) {
      int j = lane * 64 + jb;
      if (j < 1000 && sc0[bl * 1000 + j] > -0.5) keepw |= (1ull << jb);
    }
  }
  u64 m0 = 0, m1 = 0, m2 = 0, m3 = 0;
  if (lane < 16) {
    m0 = gm[0 * 16 + lane]; m1 = gm[1 * 16 + lane];
    m2 = gm[2 * 16 + lane]; m3 = gm[3 * 16 + lane];
  }
  for (int i = 0; i < 1000; i += 4) {
    u64 n0 = 0, n1 = 0, n2 = 0, n3 = 0;
    if (lane < 16 && i + 4 < 1000) {
      n0 = gm[(i + 4) * 16 + lane]; n1 = gm[(i + 5) * 16 + lane];
      n2 = gm[(i + 6) * 16 + lane]; n3 = gm[(i + 7) * 16 + lane];
    }
    { u64 kw = __shfl(keepw, (i    ) >> 6); if ((kw >> ((i    ) & 63)) & 1) { if (lane < 16) keepw &= ~m0; } }
    { u64 kw = __shfl(keepw, (i + 1) >> 6); if ((kw >> ((i + 1) & 63)) & 1) { if (lane < 16) keepw &= ~m1; } }
    { u64 kw = __shfl(keepw, (i + 2) >> 6); if ((kw >> ((i + 2) & 63)) & 1) { if (lane < 16) keepw &= ~m2; } }
    { u64 kw = __shfl(keepw, (i + 3) >> 6); if ((kw >> ((i + 3) & 63)) & 1) { if (lane < 16) keepw &= ~m3; } }
    m0 = n0; m1 = n1; m2 = n2; m3 = n3;
  }
  if (lane < 16) {
    for (int jb = 0; jb < 64; ++jb) {
      int j = lane * 64 + jb;
      if (j < 1000) {
        double ss = sc0[bl * 1000 + j];
        sc0[bl * 1000 + j] = ((keepw >> jb) & 1) ? ss : -1.0;
      }
    }
  }
}

__global__ __launch_bounds__(1024) void final_k(const double* __restrict__ sc0,
                                                const double* __restrict__ boxes,
                                                float* __restrict__ out) {
  int b = blockIdx.x;
  __shared__ u64 s[8192];
  for (int i = threadIdx.x; i < 8192; i += 1024) {
    u64 v = 0;
    if (i < 5000) {
      u64 k = d2k(sc0[b * 5000 + i]);
      v = ((k >> 18) << 18) | (u64)(0x3FFFFu - (u32)i);
    }
    s[i] = v;
  }
  __syncthreads();
  bitonic_desc_n(s, 8192);
  for (int r = threadIdx.x; r < 1000; r += 1024) {
    u64 v = s[r];
    int idx = (int)(0x3FFFFu - (u32)(v & 0x3FFFFu));
    double score = sc0[b * 5000 + idx];
    const double* bp = boxes + (size_t)(b * 5000 + idx) * 4;
    float* op = out + ((size_t)b * 1000 + r) * 5;
    op[0] = (float)bp[0]; op[1] = (float)bp[1];
    op[2] = (float)bp[2]; op[3] = (float)bp[3];
    op[4] = (float)score;
  }
}

// ---------------- host ----------------
extern "C" void kernel_launch(void* const* d_in, const int* in_sizes, int n_in,
                              void* d_out, int out_size, void* d_ws, size_t ws_size,
                              hipStream_t stream) {
  const float* p[5];
  for (int i = 0; i < 5; ++i) p[i] = (const float*)d_in[i];
  const float* conv_w = (const float*)d_in[5];
  const float* conv_b = (const float*)d_in[6];
  const float* cls_w  = (const float*)d_in[7];
  const float* cls_b  = (const float*)d_in[8];
  const float* reg_w  = (const float*)d_in[9];
  const float* reg_b  = (const float*)d_in[10];
  float* out = (float*)d_out;

  char* ws = (char*)d_ws;
  size_t off = 0;
  auto alloc = [&](size_t bytes) -> void* {
    void* pt = ws + off;
    off = (off + bytes + 255) & ~(size_t)255;
    return pt;
  };
  const size_t XTB = (size_t)2 * PXPAD * 256 * 2 + 65536;     // 85.0 MB per array
  float*  wt       = (float*) alloc(2304ull * 256 * 4);       // 2.36 MB (rescore)
  short*  wbh      = (short*) alloc(73728ull * 8 * 2);        // 1.18 MB
  short*  xh       = (short*) alloc(XTB);                     // 85 MB
  short*  xl       = (short*) alloc(XTB);                     // 85 MB
  float*  scr32    = (float*) alloc(2ull * ATOT * 4);         // 1.94 MB
  double* scr64    = (double*)alloc(2ull * ATOT * 8);         // 3.89 MB
  double* reg64    = (double*)alloc(2ull * ATOT * 4 * 8);     // 15.55 MB
  u32*    hist     = (u32*)   alloc(40ull * 65536 * 4);       // 10.5 MB (4 replicas)
  int*    meta     = (int*)   alloc(10ull * 8 * 4);
  u32*    complist = (u32*)   alloc(10ull * 8192 * 4);
  u64*    comp64   = (u64*)   alloc(10ull * 8192 * 8);
  u8*     flags    = (u8*)    alloc(2ull * PXTOT);
  u32*    worklist = (u32*)   alloc(65536ull * 4);
  int*    wlcount  = (int*)   alloc(256);
  int*    topidx   = (int*)   alloc(10ull * 1000 * 4);
  double* boxes    = (double*)alloc(2ull * 5000 * 4 * 8);
  double* sc0      = (double*)alloc(2ull * 5000 * 8);
  u64*    gmask    = (u64*)   alloc(10ull * 1000 * 16 * 8);

  wtrans_k<<<(2304 * 256 + 255) / 256, 256, 0, stream>>>(conv_w, wt);
  wcvt_k<<<288, 256, 0, stream>>>(conv_w, wbh);
  border_zero_k<<<(2 * 1974 * 8 + 255) / 256, 256, 0, stream>>>(xh, xl);
  xcvt_k<<<5064, 256, 0, stream>>>(p[0], p[1], p[2], p[3], p[4], xh, xl);
  conv_mfma_k<<<2876, 256, 0, stream>>>(xh, wbh, conv_b, cls_w, cls_b, scr32);

  int nblk = (2 * ATOT + 255) / 256;
  hipMemsetAsync(hist, 0, 40ull * 65536 * 4, stream);
  hist_hi_k<<<nblk, 256, 0, stream>>>(scr32, hist);
  scan_hi_k<<<10, 256, 0, stream>>>(hist, meta);
  hipMemsetAsync(hist, 0, 40ull * 65536 * 4, stream);
  hist_lo_k<<<nblk, 256, 0, stream>>>(scr32, meta, hist);
  scan_lo_k<<<10, 256, 0, stream>>>(hist, meta);

  hipMemsetAsync(flags, 0, 2ull * PXTOT, stream);
  hipMemsetAsync(wlcount, 0, 4, stream);
  compact_k<<<nblk, 256, 0, stream>>>(scr32, meta, complist, flags);
  pxcompact_k<<<(2 * PXTOT + 255) / 256, 256, 0, stream>>>(flags, worklist, wlcount);

  rescore_k<<<RSG, 256, 0, stream>>>(xh, xl, wt, conv_b, cls_w, cls_b, reg_w, reg_b,
                                     worklist, wlcount, scr64, reg64);

  buildkeys_k<<<10, 256, 0, stream>>>(complist, meta, scr64, comp64);
  sort_level_k<<<10, 1024, 0, stream>>>(comp64, meta, topidx);
  decode_k<<<40, 256, 0, stream>>>(topidx, scr64, reg64, boxes, sc0);
  nms_mask_k<<<40, 256, 0, stream>>>(boxes, gmask);
  nms_scan_k<<<10, 64, 0, stream>>>(sc0, gmask);
  final_k<<<2, 1024, 0, stream>>>(sc0, boxes, out);
}